// Round 3
// baseline (1252.372 us; speedup 1.0000x reference)
//
#include <hip/hip_runtime.h>

#define NNODES 20000
#define NEDGES 320000
#define HID 128
#define NL 4

constexpr int NH = NNODES * HID;
#define BN_INV (1.0f / (float)NNODES)
#define XPAD 132

// ---------------------------------------------------------------- embed
__global__ __launch_bounds__(256) void k_embed(const float* __restrict__ h,
    const float* __restrict__ ew, const float* __restrict__ eb, float* __restrict__ x)
{
    int i = blockIdx.x * 256 + threadIdx.x;          // exactly NH threads
    int nrow = i >> 7, j = i & 127;
    x[i] = fmaf(h[nrow * 2], ew[j], fmaf(h[nrow * 2 + 1], ew[HID + j], eb[j]));
}

// ---------------------------------------------------------------- CSR build
__global__ __launch_bounds__(256) void k_hist(const int* __restrict__ dst,
    int* __restrict__ deg)
{
    int e = blockIdx.x * 256 + threadIdx.x;          // exactly NEDGES threads
    atomicAdd(&deg[dst[e]], 1);
}

__global__ __launch_bounds__(1024) void k_scan(const int* __restrict__ deg,
    int* __restrict__ off)
{
    __shared__ int part[1024];
    const int t = threadIdx.x;
    const int lo = t * 20, hi = min(lo + 20, NNODES);
    int s = 0;
    for (int i = lo; i < hi; ++i) s += deg[i];
    part[t] = s;
    __syncthreads();
    for (int d = 1; d < 1024; d <<= 1) {
        int v = (t >= d) ? part[t - d] : 0;
        __syncthreads();
        part[t] += v;
        __syncthreads();
    }
    int base = part[t] - s;                          // exclusive prefix
    for (int i = lo; i < hi; ++i) { off[i] = base; base += deg[i]; }
}

// fill: bump off (exclusive->inclusive), store src (u16) + original edge id
__global__ __launch_bounds__(256) void k_fill(const int* __restrict__ src,
    const int* __restrict__ dst, int* __restrict__ off,
    unsigned short* __restrict__ eidx, int* __restrict__ epos)
{
    int e = blockIdx.x * 256 + threadIdx.x;          // exactly NEDGES threads
    int p = atomicAdd(&off[dst[e]], 1);
    eidx[p] = (unsigned short)src[e];
    epos[p] = e;
}

// ------------------------------------------- pull-mode aggregate (no atomics)
__global__ __launch_bounds__(256) void k_gather(const float* __restrict__ x,
    const int* __restrict__ off, const unsigned short* __restrict__ eidx,
    const float* __restrict__ eps, int layer, float* __restrict__ t)
{
    int tid = blockIdx.x * 256 + threadIdx.x;        // NNODES*32 threads exactly
    int n = tid >> 5, l = tid & 31;
    int start = (n == 0) ? 0 : off[n - 1];
    int end = off[n];
    const float4* xr = reinterpret_cast<const float4*>(x);
    float4 a = xr[(size_t)n * 32 + l];
    float e1 = 1.0f + eps[layer];
    float4 acc = make_float4(a.x * e1, a.y * e1, a.z * e1, a.w * e1);
    int e = start;
    for (; e + 1 < end; e += 2) {
        int s0 = eidx[e], s1 = eidx[e + 1];
        float4 v0 = xr[(size_t)s0 * 32 + l];
        float4 v1 = xr[(size_t)s1 * 32 + l];
        acc.x += v0.x + v1.x; acc.y += v0.y + v1.y;
        acc.z += v0.z + v1.z; acc.w += v0.w + v1.w;
    }
    if (e < end) {
        float4 v = xr[(size_t)eidx[e] * 32 + l];
        acc.x += v.x; acc.y += v.y; acc.z += v.z; acc.w += v.w;
    }
    reinterpret_cast<float4*>(t)[(size_t)n * 32 + l] = acc;
}

// ------------------------------------------------------- GEMM + stat epilogue
// C[N,128] = X@W + bias ; partial BN sums (s,q) atomically into sums[256].
// 32 rows/block, 625 blocks, thread tile 2x8. N%32==0 -> no bounds checks.
__global__ __launch_bounds__(256) void k_gemm_stat(const float* __restrict__ X,
    const float* __restrict__ W, const float* __restrict__ bias,
    float* __restrict__ Cm, float* __restrict__ sums)
{
    __shared__ float Xs[32][XPAD];
    __shared__ float ls[128], lq[128];
    const int tid = threadIdx.x;
    const int br = blockIdx.x * 32;
    if (tid < 128) { ls[tid] = 0.f; lq[tid] = 0.f; }
    #pragma unroll
    for (int it = 0; it < 4; ++it) {
        int f = tid + it * 256;
        int r = f >> 5, kq = (f & 31) << 2;
        *reinterpret_cast<float4*>(&Xs[r][kq]) =
            *reinterpret_cast<const float4*>(X + (size_t)(br + r) * HID + kq);
    }
    __syncthreads();
    const int j0 = (tid & 15) * 8;
    const int r0 = (tid >> 4) * 2;
    float acc[2][8];
    #pragma unroll
    for (int r = 0; r < 2; ++r)
        #pragma unroll
        for (int c = 0; c < 8; ++c) acc[r][c] = 0.f;

    for (int k = 0; k < 128; ++k) {
        const float4 wa = *reinterpret_cast<const float4*>(W + k * HID + j0);
        const float4 wb = *reinterpret_cast<const float4*>(W + k * HID + j0 + 4);
        const float w[8] = {wa.x, wa.y, wa.z, wa.w, wb.x, wb.y, wb.z, wb.w};
        const float x0 = Xs[r0][k], x1 = Xs[r0 + 1][k];
        #pragma unroll
        for (int c = 0; c < 8; ++c) {
            acc[0][c] = fmaf(x0, w[c], acc[0][c]);
            acc[1][c] = fmaf(x1, w[c], acc[1][c]);
        }
    }
    float s8[8], q8[8];
    #pragma unroll
    for (int c = 0; c < 8; ++c) {
        float bv = bias[j0 + c];
        float v0 = acc[0][c] + bv, v1 = acc[1][c] + bv;
        acc[0][c] = v0; acc[1][c] = v1;
        s8[c] = v0 + v1;
        q8[c] = fmaf(v0, v0, v1 * v1);
    }
    #pragma unroll
    for (int r = 0; r < 2; ++r) {
        float* cp = Cm + (size_t)(br + r0 + r) * HID + j0;
        *reinterpret_cast<float4*>(cp)     = make_float4(acc[r][0], acc[r][1], acc[r][2], acc[r][3]);
        *reinterpret_cast<float4*>(cp + 4) = make_float4(acc[r][4], acc[r][5], acc[r][6], acc[r][7]);
    }
    #pragma unroll
    for (int c = 0; c < 8; ++c) {
        atomicAdd(&ls[j0 + c], s8[c]);
        atomicAdd(&lq[j0 + c], q8[c]);
    }
    __syncthreads();
    if (tid < 128) {
        atomicAdd(&sums[tid], ls[tid]);
        atomicAdd(&sums[128 + tid], lq[tid]);
    }
}

// Same, but input transformed by BN(sIn,g,b)+ReLU during LDS staging.
__global__ __launch_bounds__(256) void k_gemm_bnin_stat(const float* __restrict__ X,
    const float* __restrict__ sIn, const float* __restrict__ g, const float* __restrict__ b,
    const float* __restrict__ W, const float* __restrict__ bias,
    float* __restrict__ Cm, float* __restrict__ sums)
{
    __shared__ float Xs[32][XPAD];
    __shared__ float ac[256];
    __shared__ float ls[128], lq[128];
    const int tid = threadIdx.x;
    const int br = blockIdx.x * 32;
    if (tid < 128) {
        float m = sIn[tid] * BN_INV;
        float var = fmaf(-m, m, sIn[128 + tid] * BN_INV);
        float a = g[tid] * rsqrtf(var + 1e-5f);
        ac[tid] = a;
        ac[128 + tid] = fmaf(-m, a, b[tid]);
        ls[tid] = 0.f; lq[tid] = 0.f;
    }
    __syncthreads();
    #pragma unroll
    for (int it = 0; it < 4; ++it) {
        int f = tid + it * 256;
        int r = f >> 5, kq = (f & 31) << 2;
        float4 v = *reinterpret_cast<const float4*>(X + (size_t)(br + r) * HID + kq);
        v.x = fmaxf(fmaf(ac[kq + 0], v.x, ac[128 + kq + 0]), 0.f);
        v.y = fmaxf(fmaf(ac[kq + 1], v.y, ac[128 + kq + 1]), 0.f);
        v.z = fmaxf(fmaf(ac[kq + 2], v.z, ac[128 + kq + 2]), 0.f);
        v.w = fmaxf(fmaf(ac[kq + 3], v.w, ac[128 + kq + 3]), 0.f);
        *reinterpret_cast<float4*>(&Xs[r][kq]) = v;
    }
    __syncthreads();
    const int j0 = (tid & 15) * 8;
    const int r0 = (tid >> 4) * 2;
    float acc[2][8];
    #pragma unroll
    for (int r = 0; r < 2; ++r)
        #pragma unroll
        for (int c = 0; c < 8; ++c) acc[r][c] = 0.f;

    for (int k = 0; k < 128; ++k) {
        const float4 wa = *reinterpret_cast<const float4*>(W + k * HID + j0);
        const float4 wb = *reinterpret_cast<const float4*>(W + k * HID + j0 + 4);
        const float w[8] = {wa.x, wa.y, wa.z, wa.w, wb.x, wb.y, wb.z, wb.w};
        const float x0 = Xs[r0][k], x1 = Xs[r0 + 1][k];
        #pragma unroll
        for (int c = 0; c < 8; ++c) {
            acc[0][c] = fmaf(x0, w[c], acc[0][c]);
            acc[1][c] = fmaf(x1, w[c], acc[1][c]);
        }
    }
    float s8[8], q8[8];
    #pragma unroll
    for (int c = 0; c < 8; ++c) {
        float bv = bias[j0 + c];
        float v0 = acc[0][c] + bv, v1 = acc[1][c] + bv;
        acc[0][c] = v0; acc[1][c] = v1;
        s8[c] = v0 + v1;
        q8[c] = fmaf(v0, v0, v1 * v1);
    }
    #pragma unroll
    for (int r = 0; r < 2; ++r) {
        float* cp = Cm + (size_t)(br + r0 + r) * HID + j0;
        *reinterpret_cast<float4*>(cp)     = make_float4(acc[r][0], acc[r][1], acc[r][2], acc[r][3]);
        *reinterpret_cast<float4*>(cp + 4) = make_float4(acc[r][4], acc[r][5], acc[r][6], acc[r][7]);
    }
    #pragma unroll
    for (int c = 0; c < 8; ++c) {
        atomicAdd(&ls[j0 + c], s8[c]);
        atomicAdd(&lq[j0 + c], q8[c]);
    }
    __syncthreads();
    if (tid < 128) {
        atomicAdd(&sums[tid], ls[tid]);
        atomicAdd(&sums[128 + tid], lq[tid]);
    }
}

// Dual GEMM for heads: A = X@W1[0:128] + b1 ; B = X@W1[128:256]. 32-row tiles.
__global__ __launch_bounds__(256) void k_gemm_head(const float* __restrict__ X,
    const float* __restrict__ W1, const float* __restrict__ b1,
    float* __restrict__ A, float* __restrict__ Bm)
{
    __shared__ float Xs[32][XPAD];
    const int tid = threadIdx.x;
    const int br = blockIdx.x * 32;
    #pragma unroll
    for (int it = 0; it < 4; ++it) {
        int f = tid + it * 256;
        int r = f >> 5, kq = (f & 31) << 2;
        *reinterpret_cast<float4*>(&Xs[r][kq]) =
            *reinterpret_cast<const float4*>(X + (size_t)(br + r) * HID + kq);
    }
    __syncthreads();
    const int j0 = (tid & 15) * 8;
    const int r0 = (tid >> 4) * 2;
    float accA[2][8], accB[2][8];
    #pragma unroll
    for (int r = 0; r < 2; ++r)
        #pragma unroll
        for (int c = 0; c < 8; ++c) { accA[r][c] = 0.f; accB[r][c] = 0.f; }

    for (int k = 0; k < 128; ++k) {
        const float4 wa0 = *reinterpret_cast<const float4*>(W1 + k * HID + j0);
        const float4 wa1 = *reinterpret_cast<const float4*>(W1 + k * HID + j0 + 4);
        const float4 wb0 = *reinterpret_cast<const float4*>(W1 + (HID + k) * HID + j0);
        const float4 wb1 = *reinterpret_cast<const float4*>(W1 + (HID + k) * HID + j0 + 4);
        const float wa[8] = {wa0.x, wa0.y, wa0.z, wa0.w, wa1.x, wa1.y, wa1.z, wa1.w};
        const float wb[8] = {wb0.x, wb0.y, wb0.z, wb0.w, wb1.x, wb1.y, wb1.z, wb1.w};
        const float x0 = Xs[r0][k], x1 = Xs[r0 + 1][k];
        #pragma unroll
        for (int c = 0; c < 8; ++c) {
            accA[0][c] = fmaf(x0, wa[c], accA[0][c]);
            accA[1][c] = fmaf(x1, wa[c], accA[1][c]);
            accB[0][c] = fmaf(x0, wb[c], accB[0][c]);
            accB[1][c] = fmaf(x1, wb[c], accB[1][c]);
        }
    }
    #pragma unroll
    for (int r = 0; r < 2; ++r) {
        size_t rowoff = (size_t)(br + r0 + r) * HID + j0;
        float4 a0 = make_float4(accA[r][0] + b1[j0], accA[r][1] + b1[j0 + 1],
                                accA[r][2] + b1[j0 + 2], accA[r][3] + b1[j0 + 3]);
        float4 a1 = make_float4(accA[r][4] + b1[j0 + 4], accA[r][5] + b1[j0 + 5],
                                accA[r][6] + b1[j0 + 6], accA[r][7] + b1[j0 + 7]);
        *reinterpret_cast<float4*>(A + rowoff)     = a0;
        *reinterpret_cast<float4*>(A + rowoff + 4) = a1;
        *reinterpret_cast<float4*>(Bm + rowoff)     = make_float4(accB[r][0], accB[r][1], accB[r][2], accB[r][3]);
        *reinterpret_cast<float4*>(Bm + rowoff + 4) = make_float4(accB[r][4], accB[r][5], accB[r][6], accB[r][7]);
    }
}

// ------------------------------------- elementwise BN passes over v
// pass 1: w = relu(app(v)); partial stats of w -> s2 (w not materialized)
__global__ __launch_bounds__(256) void k_app_stat(const float* __restrict__ v,
    const float* __restrict__ s1, const float* __restrict__ g, const float* __restrict__ b,
    float* __restrict__ s2)
{
    __shared__ float ac[256];
    __shared__ float ls[128], lq[128];
    const int tid = threadIdx.x;
    if (tid < 128) {
        float m = s1[tid] * BN_INV;
        float var = fmaf(-m, m, s1[128 + tid] * BN_INV);
        float a = g[tid] * rsqrtf(var + 1e-5f);
        ac[tid] = a;
        ac[128 + tid] = fmaf(-m, a, b[tid]);
        ls[tid] = 0.f; lq[tid] = 0.f;
    }
    __syncthreads();
    const size_t base = (size_t)blockIdx.x * 2048 + tid * 8;   // grid 1250
    const int j0 = (tid & 15) * 8;
    float4 v0 = *reinterpret_cast<const float4*>(v + base);
    float4 v1 = *reinterpret_cast<const float4*>(v + base + 4);
    float w[8] = {v0.x, v0.y, v0.z, v0.w, v1.x, v1.y, v1.z, v1.w};
    #pragma unroll
    for (int c = 0; c < 8; ++c) {
        w[c] = fmaxf(fmaf(ac[j0 + c], w[c], ac[128 + j0 + c]), 0.f);
        atomicAdd(&ls[j0 + c], w[c]);
        atomicAdd(&lq[j0 + c], w[c] * w[c]);
    }
    __syncthreads();
    if (tid < 128) {
        atomicAdd(&s2[tid], ls[tid]);
        atomicAdd(&s2[128 + tid], lq[tid]);
    }
}

// pass 2: x += relu(gin(relu(app(v))))
__global__ __launch_bounds__(256) void k_applyresid(const float* __restrict__ v,
    const float* __restrict__ s1, const float* __restrict__ ga, const float* __restrict__ ba,
    const float* __restrict__ s2, const float* __restrict__ gg, const float* __restrict__ bg,
    float* __restrict__ x)
{
    __shared__ float aca[256], acg[256];
    const int tid = threadIdx.x;
    if (tid < 128) {
        float m = s1[tid] * BN_INV;
        float var = fmaf(-m, m, s1[128 + tid] * BN_INV);
        float a = ga[tid] * rsqrtf(var + 1e-5f);
        aca[tid] = a;
        aca[128 + tid] = fmaf(-m, a, ba[tid]);
        float m2 = s2[tid] * BN_INV;
        float var2 = fmaf(-m2, m2, s2[128 + tid] * BN_INV);
        float a2 = gg[tid] * rsqrtf(var2 + 1e-5f);
        acg[tid] = a2;
        acg[128 + tid] = fmaf(-m2, a2, bg[tid]);
    }
    __syncthreads();
    const size_t base = (size_t)blockIdx.x * 2048 + tid * 8;   // grid 1250
    const int j0 = (tid & 15) * 8;
    float4 v0 = *reinterpret_cast<const float4*>(v + base);
    float4 v1 = *reinterpret_cast<const float4*>(v + base + 4);
    float4 x0 = *reinterpret_cast<const float4*>(x + base);
    float4 x1 = *reinterpret_cast<const float4*>(x + base + 4);
    float w[8] = {v0.x, v0.y, v0.z, v0.w, v1.x, v1.y, v1.z, v1.w};
    float xo[8] = {x0.x, x0.y, x0.z, x0.w, x1.x, x1.y, x1.z, x1.w};
    #pragma unroll
    for (int c = 0; c < 8; ++c) {
        float t = fmaxf(fmaf(aca[j0 + c], w[c], aca[128 + j0 + c]), 0.f);
        xo[c] += fmaxf(fmaf(acg[j0 + c], t, acg[128 + j0 + c]), 0.f);
    }
    *reinterpret_cast<float4*>(x + base)     = make_float4(xo[0], xo[1], xo[2], xo[3]);
    *reinterpret_cast<float4*>(x + base + 4) = make_float4(xo[4], xo[5], xo[6], xo[7]);
}

// ---------------------------------------------------- edge head (dst-CSR)
// wave = 1 dst node; B[d] loaded once; 2 edges in flight (two 32-lane halves)
__global__ __launch_bounds__(256) void k_edge_csr(const float* __restrict__ A,
    const float* __restrict__ Bm, const int* __restrict__ off,
    const unsigned short* __restrict__ eidx, const int* __restrict__ epos,
    const float* __restrict__ w2, const float* __restrict__ b2,
    float* __restrict__ out, int accumulate)
{
    const int wid = (blockIdx.x * 256 + threadIdx.x) >> 6;   // node; grid 5000 blocks
    const int lane = threadIdx.x & 63;
    const int half = lane >> 5, l = lane & 31;
    const int start = wid ? off[wid - 1] : 0;
    const int end = off[wid];
    const float4 bv = *reinterpret_cast<const float4*>(Bm + (size_t)wid * HID + l * 4);
    const float4 w01 = *reinterpret_cast<const float4*>(w2 + l * 8);
    const float4 w23 = *reinterpret_cast<const float4*>(w2 + l * 8 + 4);
    const float bias0 = b2[0], bias1 = b2[1];
    for (int e = start + half; e < end; e += 2) {
        int s = eidx[e];
        const float4 a = *reinterpret_cast<const float4*>(A + (size_t)s * HID + l * 4);
        float z0 = fmaxf(a.x + bv.x, 0.f);
        float z1 = fmaxf(a.y + bv.y, 0.f);
        float z2 = fmaxf(a.z + bv.z, 0.f);
        float z3 = fmaxf(a.w + bv.w, 0.f);
        float s0 = z0 * w01.x + z1 * w01.z + z2 * w23.x + z3 * w23.z;
        float s1 = z0 * w01.y + z1 * w01.w + z2 * w23.y + z3 * w23.w;
        #pragma unroll
        for (int m = 16; m >= 1; m >>= 1) {
            s0 += __shfl_xor(s0, m);
            s1 += __shfl_xor(s1, m);
        }
        if (l == 0) {
            int oe = epos[e];
            float o0 = s0 + bias0, o1 = s1 + bias1;
            if (accumulate) {
                out[oe * 2 + 0] += o0;
                out[oe * 2 + 1] += o1;
            } else {
                out[oe * 2 + 0] = o0;
                out[oe * 2 + 1] = o1;
            }
        }
    }
}

// ---------------------------------------------------------------- launch
extern "C" void kernel_launch(void* const* d_in, const int* in_sizes, int n_in,
                              void* d_out, int out_size, void* d_ws, size_t ws_size,
                              hipStream_t stream)
{
    const float* h        = (const float*)d_in[0];
    const int*   src      = (const int*)d_in[1];
    const int*   dst      = (const int*)d_in[2];
    const float* emb_w    = (const float*)d_in[3];
    const float* emb_b    = (const float*)d_in[4];
    const float* eps      = (const float*)d_in[5];
    const float* mlp_w1   = (const float*)d_in[6];
    const float* mlp_b1   = (const float*)d_in[7];
    const float* mlp_bn_g = (const float*)d_in[8];
    const float* mlp_bn_b = (const float*)d_in[9];
    const float* mlp_w2   = (const float*)d_in[10];
    const float* mlp_b2   = (const float*)d_in[11];
    const float* app_bn_g = (const float*)d_in[12];
    const float* app_bn_b = (const float*)d_in[13];
    const float* gin_bn_g = (const float*)d_in[14];
    const float* gin_bn_b = (const float*)d_in[15];
    const float* pred_w1  = (const float*)d_in[16];
    const float* pred_b1  = (const float*)d_in[17];
    const float* pred_w2  = (const float*)d_in[18];
    const float* pred_b2  = (const float*)d_in[19];
    float* out = (float*)d_out;

    float* ws   = (float*)d_ws;
    float* x    = ws;                       // [N,128]
    float* tmp1 = ws + NH;                  // [N,128]
    float* tmp2 = ws + 2 * (size_t)NH;      // [N,128]
    float* sums = ws + 3 * (size_t)NH;      // [12][256]
    int*   off  = (int*)(sums + 12 * 256);  // [N]
    int*   deg  = off + NNODES;             // [N]
    int*   epos = deg + NNODES;             // [E]
    unsigned short* eidx = (unsigned short*)(epos + NEDGES); // [E]

    const int NB = NH / 256;                    // 10000
    const int EB = NEDGES / 256;                // 1250
    const int GB = NNODES / 32;                 // 625
    const int AGB = NNODES * 32 / 256;          // 2500
    const int VB = NH / 2048;                   // 1250
    const int CEB = NNODES / 4;                 // 5000 (4 waves/block)

    // ---- CSR build (graph static across layers)
    hipMemsetAsync(deg, 0, NNODES * sizeof(int), stream);
    hipMemsetAsync(sums, 0, 12 * 256 * sizeof(float), stream);
    k_hist<<<EB, 256, 0, stream>>>(dst, deg);
    k_scan<<<1, 1024, 0, stream>>>(deg, off);
    k_fill<<<EB, 256, 0, stream>>>(src, dst, off, eidx, epos);

    k_embed<<<NB, 256, 0, stream>>>(h, emb_w, emb_b, x);

    // head 0
    k_gemm_head<<<GB, 256, 0, stream>>>(x, pred_w1, pred_b1, tmp1, tmp2);
    k_edge_csr<<<CEB, 256, 0, stream>>>(tmp1, tmp2, off, eidx, epos,
                                        pred_w2, pred_b2, out, 0);

    for (int i = 0; i < NL; ++i) {
        float* s0 = sums + (i * 3 + 0) * 256;
        float* s1 = sums + (i * 3 + 1) * 256;
        float* s2 = sums + (i * 3 + 2) * 256;

        // t = (1+eps)*x + sum_in x[src]
        k_gather<<<AGB, 256, 0, stream>>>(x, off, eidx, eps, i, tmp1);

        // u = t @ W1 + b1 ; stats(u) -> s0
        k_gemm_stat<<<GB, 256, 0, stream>>>(tmp1, mlp_w1 + (size_t)i * HID * HID,
                                            mlp_b1 + i * HID, tmp2, s0);
        // v = relu(BN_s0(u)) @ W2 + b2 ; stats(v) -> s1
        k_gemm_bnin_stat<<<GB, 256, 0, stream>>>(tmp2, s0, mlp_bn_g + i * HID,
                                                 mlp_bn_b + i * HID,
                                                 mlp_w2 + (size_t)i * HID * HID,
                                                 mlp_b2 + i * HID, tmp1, s1);
        // stats(relu(BN_s1(v))) -> s2
        k_app_stat<<<VB, 256, 0, stream>>>(tmp1, s1, app_bn_g + i * HID,
                                           app_bn_b + i * HID, s2);
        // x += relu(BN_s2(relu(BN_s1(v))))
        k_applyresid<<<VB, 256, 0, stream>>>(tmp1, s1, app_bn_g + i * HID,
                                             app_bn_b + i * HID, s2,
                                             gin_bn_g + i * HID, gin_bn_b + i * HID, x);

        // head i+1
        k_gemm_head<<<GB, 256, 0, stream>>>(x, pred_w1 + (size_t)(i + 1) * 256 * HID,
                                            pred_b1 + (i + 1) * HID, tmp1, tmp2);
        k_edge_csr<<<CEB, 256, 0, stream>>>(tmp1, tmp2, off, eidx, epos,
                                            pred_w2 + (i + 1) * HID * 2,
                                            pred_b2 + (i + 1) * 2, out, 1);
    }
}

// Round 4
// 938.484 us; speedup vs baseline: 1.3345x; 1.3345x over previous
//
#include <hip/hip_runtime.h>

#define NNODES 20000
#define NEDGES 320000
#define HID 128
#define NL 4

constexpr int NH = NNODES * HID;
#define BN_INV (1.0f / (float)NNODES)
#define XPAD 132
#define ROWS 80          // rows per GEMM block; 20000/80 = 250 blocks
#define RPT 5            // rows per thread (16 row-groups * 5)

// ---------------------------------------------------------------- embed
__global__ __launch_bounds__(256) void k_embed(const float* __restrict__ h,
    const float* __restrict__ ew, const float* __restrict__ eb, float* __restrict__ x)
{
    int i = blockIdx.x * 256 + threadIdx.x;          // exactly NH threads
    int nrow = i >> 7, j = i & 127;
    x[i] = fmaf(h[nrow * 2], ew[j], fmaf(h[nrow * 2 + 1], ew[HID + j], eb[j]));
}

// ---------------------------------------------------------------- CSR build
__global__ __launch_bounds__(256) void k_hist(const int* __restrict__ dst,
    int* __restrict__ deg)
{
    int e = blockIdx.x * 256 + threadIdx.x;          // exactly NEDGES threads
    atomicAdd(&deg[dst[e]], 1);
}

__global__ __launch_bounds__(1024) void k_scan(const int* __restrict__ deg,
    int* __restrict__ off)
{
    __shared__ int part[1024];
    const int t = threadIdx.x;
    const int lo = t * 20, hi = min(lo + 20, NNODES);
    int s = 0;
    for (int i = lo; i < hi; ++i) s += deg[i];
    part[t] = s;
    __syncthreads();
    for (int d = 1; d < 1024; d <<= 1) {
        int v = (t >= d) ? part[t - d] : 0;
        __syncthreads();
        part[t] += v;
        __syncthreads();
    }
    int base = part[t] - s;                          // exclusive prefix
    for (int i = lo; i < hi; ++i) { off[i] = base; base += deg[i]; }
}

__global__ __launch_bounds__(256) void k_fill(const int* __restrict__ src,
    const int* __restrict__ dst, int* __restrict__ off,
    unsigned short* __restrict__ eidx, int* __restrict__ epos)
{
    int e = blockIdx.x * 256 + threadIdx.x;          // exactly NEDGES threads
    int p = atomicAdd(&off[dst[e]], 1);
    eidx[p] = (unsigned short)src[e];
    epos[p] = e;
}

// ------------------------------------------- pull-mode aggregate (no atomics)
__global__ __launch_bounds__(256) void k_gather(const float* __restrict__ x,
    const int* __restrict__ off, const unsigned short* __restrict__ eidx,
    const float* __restrict__ eps, int layer, float* __restrict__ t)
{
    int tid = blockIdx.x * 256 + threadIdx.x;        // NNODES*32 threads exactly
    int n = tid >> 5, l = tid & 31;
    int start = (n == 0) ? 0 : off[n - 1];
    int end = off[n];
    const float4* xr = reinterpret_cast<const float4*>(x);
    float4 a = xr[(size_t)n * 32 + l];
    float e1 = 1.0f + eps[layer];
    float4 acc = make_float4(a.x * e1, a.y * e1, a.z * e1, a.w * e1);
    int e = start;
    for (; e + 1 < end; e += 2) {
        int s0 = eidx[e], s1 = eidx[e + 1];
        float4 v0 = xr[(size_t)s0 * 32 + l];
        float4 v1 = xr[(size_t)s1 * 32 + l];
        acc.x += v0.x + v1.x; acc.y += v0.y + v1.y;
        acc.z += v0.z + v1.z; acc.w += v0.w + v1.w;
    }
    if (e < end) {
        float4 v = xr[(size_t)eidx[e] * 32 + l];
        acc.x += v.x; acc.y += v.y; acc.z += v.z; acc.w += v.w;
    }
    reinterpret_cast<float4*>(t)[(size_t)n * 32 + l] = acc;
}

// --------------------------------------------- epilogue stat helper (device)
__device__ __forceinline__ void stat_reduce(float* s8, float* q8, int j0,
    float* ls, float* lq, float* sums)
{
    const int lane = threadIdx.x & 63;
    #pragma unroll
    for (int c = 0; c < 8; ++c) {
        s8[c] += __shfl_xor(s8[c], 16); s8[c] += __shfl_xor(s8[c], 32);
        q8[c] += __shfl_xor(q8[c], 16); q8[c] += __shfl_xor(q8[c], 32);
    }
    if (lane < 16) {
        #pragma unroll
        for (int c = 0; c < 8; ++c) {
            atomicAdd(&ls[j0 + c], s8[c]);
            atomicAdd(&lq[j0 + c], q8[c]);
        }
    }
    __syncthreads();
    if (threadIdx.x < 128) {
        atomicAdd(&sums[threadIdx.x], ls[threadIdx.x]);
        atomicAdd(&sums[128 + threadIdx.x], lq[threadIdx.x]);
    }
}

// ------------------------------------------------------- GEMM + stat epilogue
// C[N,128] = X@W + bias ; BN partial sums into sums[256]. 80 rows/block.
__global__ __launch_bounds__(256) void k_gemm_stat(const float* __restrict__ X,
    const float* __restrict__ W, const float* __restrict__ bias,
    float* __restrict__ Cm, float* __restrict__ sums)
{
    __shared__ float Xs[ROWS][XPAD];
    __shared__ float ls[128], lq[128];
    const int tid = threadIdx.x;
    const int br = blockIdx.x * ROWS;
    if (tid < 128) { ls[tid] = 0.f; lq[tid] = 0.f; }
    #pragma unroll
    for (int it = 0; it < 10; ++it) {
        int f = tid + it * 256;
        int r = f >> 5, kq = (f & 31) << 2;
        *reinterpret_cast<float4*>(&Xs[r][kq]) =
            *reinterpret_cast<const float4*>(X + (size_t)(br + r) * HID + kq);
    }
    __syncthreads();
    const int j0 = (tid & 15) * 8;
    const int r0 = (tid >> 4) * RPT;
    float acc[RPT][8];
    #pragma unroll
    for (int r = 0; r < RPT; ++r)
        #pragma unroll
        for (int c = 0; c < 8; ++c) acc[r][c] = 0.f;

    for (int k = 0; k < 128; ++k) {
        const float4 wa = *reinterpret_cast<const float4*>(W + k * HID + j0);
        const float4 wb = *reinterpret_cast<const float4*>(W + k * HID + j0 + 4);
        const float w[8] = {wa.x, wa.y, wa.z, wa.w, wb.x, wb.y, wb.z, wb.w};
        #pragma unroll
        for (int r = 0; r < RPT; ++r) {
            const float xv = Xs[r0 + r][k];
            #pragma unroll
            for (int c = 0; c < 8; ++c) acc[r][c] = fmaf(xv, w[c], acc[r][c]);
        }
    }
    float s8[8], q8[8];
    #pragma unroll
    for (int c = 0; c < 8; ++c) { s8[c] = 0.f; q8[c] = 0.f; }
    #pragma unroll
    for (int r = 0; r < RPT; ++r) {
        #pragma unroll
        for (int c = 0; c < 8; ++c) {
            float v = acc[r][c] + bias[j0 + c];
            acc[r][c] = v;
            s8[c] += v;
            q8[c] = fmaf(v, v, q8[c]);
        }
        float* cp = Cm + (size_t)(br + r0 + r) * HID + j0;
        *reinterpret_cast<float4*>(cp)     = make_float4(acc[r][0], acc[r][1], acc[r][2], acc[r][3]);
        *reinterpret_cast<float4*>(cp + 4) = make_float4(acc[r][4], acc[r][5], acc[r][6], acc[r][7]);
    }
    stat_reduce(s8, q8, j0, ls, lq, sums);
}

// Same, but input transformed by BN(sIn,g,b)+ReLU during LDS staging.
__global__ __launch_bounds__(256) void k_gemm_bnin_stat(const float* __restrict__ X,
    const float* __restrict__ sIn, const float* __restrict__ g, const float* __restrict__ b,
    const float* __restrict__ W, const float* __restrict__ bias,
    float* __restrict__ Cm, float* __restrict__ sums)
{
    __shared__ float Xs[ROWS][XPAD];
    __shared__ float ac[256];
    __shared__ float ls[128], lq[128];
    const int tid = threadIdx.x;
    const int br = blockIdx.x * ROWS;
    if (tid < 128) {
        float m = sIn[tid] * BN_INV;
        float var = fmaf(-m, m, sIn[128 + tid] * BN_INV);
        float a = g[tid] * rsqrtf(var + 1e-5f);
        ac[tid] = a;
        ac[128 + tid] = fmaf(-m, a, b[tid]);
        ls[tid] = 0.f; lq[tid] = 0.f;
    }
    __syncthreads();
    #pragma unroll
    for (int it = 0; it < 10; ++it) {
        int f = tid + it * 256;
        int r = f >> 5, kq = (f & 31) << 2;
        float4 v = *reinterpret_cast<const float4*>(X + (size_t)(br + r) * HID + kq);
        v.x = fmaxf(fmaf(ac[kq + 0], v.x, ac[128 + kq + 0]), 0.f);
        v.y = fmaxf(fmaf(ac[kq + 1], v.y, ac[128 + kq + 1]), 0.f);
        v.z = fmaxf(fmaf(ac[kq + 2], v.z, ac[128 + kq + 2]), 0.f);
        v.w = fmaxf(fmaf(ac[kq + 3], v.w, ac[128 + kq + 3]), 0.f);
        *reinterpret_cast<float4*>(&Xs[r][kq]) = v;
    }
    __syncthreads();
    const int j0 = (tid & 15) * 8;
    const int r0 = (tid >> 4) * RPT;
    float acc[RPT][8];
    #pragma unroll
    for (int r = 0; r < RPT; ++r)
        #pragma unroll
        for (int c = 0; c < 8; ++c) acc[r][c] = 0.f;

    for (int k = 0; k < 128; ++k) {
        const float4 wa = *reinterpret_cast<const float4*>(W + k * HID + j0);
        const float4 wb = *reinterpret_cast<const float4*>(W + k * HID + j0 + 4);
        const float w[8] = {wa.x, wa.y, wa.z, wa.w, wb.x, wb.y, wb.z, wb.w};
        #pragma unroll
        for (int r = 0; r < RPT; ++r) {
            const float xv = Xs[r0 + r][k];
            #pragma unroll
            for (int c = 0; c < 8; ++c) acc[r][c] = fmaf(xv, w[c], acc[r][c]);
        }
    }
    float s8[8], q8[8];
    #pragma unroll
    for (int c = 0; c < 8; ++c) { s8[c] = 0.f; q8[c] = 0.f; }
    #pragma unroll
    for (int r = 0; r < RPT; ++r) {
        #pragma unroll
        for (int c = 0; c < 8; ++c) {
            float v = acc[r][c] + bias[j0 + c];
            acc[r][c] = v;
            s8[c] += v;
            q8[c] = fmaf(v, v, q8[c]);
        }
        float* cp = Cm + (size_t)(br + r0 + r) * HID + j0;
        *reinterpret_cast<float4*>(cp)     = make_float4(acc[r][0], acc[r][1], acc[r][2], acc[r][3]);
        *reinterpret_cast<float4*>(cp + 4) = make_float4(acc[r][4], acc[r][5], acc[r][6], acc[r][7]);
    }
    stat_reduce(s8, q8, j0, ls, lq, sums);
}

// --------------------------------- dual-GEMM body (A,B from staged Xs) helper
#define HEAD_GEMM_BODY(W1, b1, A, Bm)                                          \
    const int j0 = (tid & 15) * 8;                                             \
    const int r0 = (tid >> 4) * RPT;                                           \
    float accA[RPT][8], accB[RPT][8];                                          \
    _Pragma("unroll")                                                          \
    for (int r = 0; r < RPT; ++r) {                                            \
        _Pragma("unroll")                                                      \
        for (int c = 0; c < 8; ++c) { accA[r][c] = 0.f; accB[r][c] = 0.f; }    \
    }                                                                          \
    for (int k = 0; k < 128; ++k) {                                            \
        const float4 wa0 = *reinterpret_cast<const float4*>(W1 + k * HID + j0);\
        const float4 wa1 = *reinterpret_cast<const float4*>(W1 + k * HID + j0 + 4);\
        const float4 wb0 = *reinterpret_cast<const float4*>(W1 + (HID + k) * HID + j0);\
        const float4 wb1 = *reinterpret_cast<const float4*>(W1 + (HID + k) * HID + j0 + 4);\
        const float wa[8] = {wa0.x, wa0.y, wa0.z, wa0.w, wa1.x, wa1.y, wa1.z, wa1.w};\
        const float wb[8] = {wb0.x, wb0.y, wb0.z, wb0.w, wb1.x, wb1.y, wb1.z, wb1.w};\
        _Pragma("unroll")                                                      \
        for (int r = 0; r < RPT; ++r) {                                        \
            const float xv = Xs[r0 + r][k];                                    \
            _Pragma("unroll")                                                  \
            for (int c = 0; c < 8; ++c) {                                      \
                accA[r][c] = fmaf(xv, wa[c], accA[r][c]);                      \
                accB[r][c] = fmaf(xv, wb[c], accB[r][c]);                      \
            }                                                                  \
        }                                                                      \
    }                                                                          \
    _Pragma("unroll")                                                          \
    for (int r = 0; r < RPT; ++r) {                                            \
        size_t rowoff = (size_t)(br + r0 + r) * HID + j0;                      \
        *reinterpret_cast<float4*>(A + rowoff) =                               \
            make_float4(accA[r][0] + b1[j0], accA[r][1] + b1[j0 + 1],          \
                        accA[r][2] + b1[j0 + 2], accA[r][3] + b1[j0 + 3]);     \
        *reinterpret_cast<float4*>(A + rowoff + 4) =                           \
            make_float4(accA[r][4] + b1[j0 + 4], accA[r][5] + b1[j0 + 5],      \
                        accA[r][6] + b1[j0 + 6], accA[r][7] + b1[j0 + 7]);     \
        *reinterpret_cast<float4*>(Bm + rowoff) =                              \
            make_float4(accB[r][0], accB[r][1], accB[r][2], accB[r][3]);       \
        *reinterpret_cast<float4*>(Bm + rowoff + 4) =                          \
            make_float4(accB[r][4], accB[r][5], accB[r][6], accB[r][7]);       \
    }

// head 0: plain input staging
__global__ __launch_bounds__(256) void k_gemm_head(const float* __restrict__ X,
    const float* __restrict__ W1, const float* __restrict__ b1,
    float* __restrict__ A, float* __restrict__ Bm)
{
    __shared__ float Xs[ROWS][XPAD];
    const int tid = threadIdx.x;
    const int br = blockIdx.x * ROWS;
    #pragma unroll
    for (int it = 0; it < 10; ++it) {
        int f = tid + it * 256;
        int r = f >> 5, kq = (f & 31) << 2;
        *reinterpret_cast<float4*>(&Xs[r][kq]) =
            *reinterpret_cast<const float4*>(X + (size_t)(br + r) * HID + kq);
    }
    __syncthreads();
    HEAD_GEMM_BODY(W1, b1, A, Bm)
}

// heads 1..L: staging computes x += relu(gin(relu(app(v)))), writes x back,
// and uses updated x as the GEMM input.
__global__ __launch_bounds__(256) void k_head_resid(const float* __restrict__ v,
    const float* __restrict__ s1, const float* __restrict__ ga, const float* __restrict__ ba,
    const float* __restrict__ s2, const float* __restrict__ gg, const float* __restrict__ bg,
    float* __restrict__ x,
    const float* __restrict__ W1, const float* __restrict__ b1,
    float* __restrict__ A, float* __restrict__ Bm)
{
    __shared__ float Xs[ROWS][XPAD];
    __shared__ float aca[256], acg[256];
    const int tid = threadIdx.x;
    const int br = blockIdx.x * ROWS;
    if (tid < 128) {
        float m = s1[tid] * BN_INV;
        float var = fmaf(-m, m, s1[128 + tid] * BN_INV);
        float a = ga[tid] * rsqrtf(var + 1e-5f);
        aca[tid] = a;
        aca[128 + tid] = fmaf(-m, a, ba[tid]);
        float m2 = s2[tid] * BN_INV;
        float var2 = fmaf(-m2, m2, s2[128 + tid] * BN_INV);
        float a2 = gg[tid] * rsqrtf(var2 + 1e-5f);
        acg[tid] = a2;
        acg[128 + tid] = fmaf(-m2, a2, bg[tid]);
    }
    __syncthreads();
    #pragma unroll
    for (int it = 0; it < 10; ++it) {
        int f = tid + it * 256;
        int r = f >> 5, kq = (f & 31) << 2;
        size_t goff = (size_t)(br + r) * HID + kq;
        float4 vv = *reinterpret_cast<const float4*>(v + goff);
        float4 xv = *reinterpret_cast<const float4*>(x + goff);
        float t0 = fmaxf(fmaf(aca[kq + 0], vv.x, aca[128 + kq + 0]), 0.f);
        float t1 = fmaxf(fmaf(aca[kq + 1], vv.y, aca[128 + kq + 1]), 0.f);
        float t2 = fmaxf(fmaf(aca[kq + 2], vv.z, aca[128 + kq + 2]), 0.f);
        float t3 = fmaxf(fmaf(aca[kq + 3], vv.w, aca[128 + kq + 3]), 0.f);
        xv.x += fmaxf(fmaf(acg[kq + 0], t0, acg[128 + kq + 0]), 0.f);
        xv.y += fmaxf(fmaf(acg[kq + 1], t1, acg[128 + kq + 1]), 0.f);
        xv.z += fmaxf(fmaf(acg[kq + 2], t2, acg[128 + kq + 2]), 0.f);
        xv.w += fmaxf(fmaf(acg[kq + 3], t3, acg[128 + kq + 3]), 0.f);
        *reinterpret_cast<float4*>(x + goff) = xv;
        *reinterpret_cast<float4*>(&Xs[r][kq]) = xv;
    }
    __syncthreads();
    HEAD_GEMM_BODY(W1, b1, A, Bm)
}

// ------------------------------------- stats of relu(app(v)) -> s2
__global__ __launch_bounds__(256) void k_app_stat(const float* __restrict__ v,
    const float* __restrict__ s1, const float* __restrict__ g, const float* __restrict__ b,
    float* __restrict__ s2)
{
    __shared__ float ac[256];
    __shared__ float ls[128], lq[128];
    const int tid = threadIdx.x;
    if (tid < 128) {
        float m = s1[tid] * BN_INV;
        float var = fmaf(-m, m, s1[128 + tid] * BN_INV);
        float a = g[tid] * rsqrtf(var + 1e-5f);
        ac[tid] = a;
        ac[128 + tid] = fmaf(-m, a, b[tid]);
        ls[tid] = 0.f; lq[tid] = 0.f;
    }
    __syncthreads();
    const size_t base = (size_t)blockIdx.x * 2048 + tid * 8;   // grid 1250
    const int j0 = (tid & 15) * 8;
    float4 v0 = *reinterpret_cast<const float4*>(v + base);
    float4 v1 = *reinterpret_cast<const float4*>(v + base + 4);
    float w[8] = {v0.x, v0.y, v0.z, v0.w, v1.x, v1.y, v1.z, v1.w};
    float s8[8], q8[8];
    #pragma unroll
    for (int c = 0; c < 8; ++c) {
        w[c] = fmaxf(fmaf(ac[j0 + c], w[c], ac[128 + j0 + c]), 0.f);
        s8[c] = w[c];
        q8[c] = w[c] * w[c];
    }
    stat_reduce(s8, q8, j0, ls, lq, s2);
}

// ---------------------------------------------------- edge head (dst-CSR)
__global__ __launch_bounds__(256) void k_edge_csr(const float* __restrict__ A,
    const float* __restrict__ Bm, const int* __restrict__ off,
    const unsigned short* __restrict__ eidx, const int* __restrict__ epos,
    const float* __restrict__ w2, const float* __restrict__ b2,
    float* __restrict__ out, int accumulate)
{
    const int wid = (blockIdx.x * 256 + threadIdx.x) >> 6;   // node; grid 5000
    const int lane = threadIdx.x & 63;
    const int half = lane >> 5, l = lane & 31;
    const int start = wid ? off[wid - 1] : 0;
    const int end = off[wid];
    const float4 bv = *reinterpret_cast<const float4*>(Bm + (size_t)wid * HID + l * 4);
    const float4 w01 = *reinterpret_cast<const float4*>(w2 + l * 8);
    const float4 w23 = *reinterpret_cast<const float4*>(w2 + l * 8 + 4);
    const float bias0 = b2[0], bias1 = b2[1];
    for (int e = start + half; e < end; e += 2) {
        int s = eidx[e];
        const float4 a = *reinterpret_cast<const float4*>(A + (size_t)s * HID + l * 4);
        float z0 = fmaxf(a.x + bv.x, 0.f);
        float z1 = fmaxf(a.y + bv.y, 0.f);
        float z2 = fmaxf(a.z + bv.z, 0.f);
        float z3 = fmaxf(a.w + bv.w, 0.f);
        float s0 = z0 * w01.x + z1 * w01.z + z2 * w23.x + z3 * w23.z;
        float s1 = z0 * w01.y + z1 * w01.w + z2 * w23.y + z3 * w23.w;
        #pragma unroll
        for (int m = 16; m >= 1; m >>= 1) {
            s0 += __shfl_xor(s0, m);
            s1 += __shfl_xor(s1, m);
        }
        if (l == 0) {
            int oe = epos[e];
            float o0 = s0 + bias0, o1 = s1 + bias1;
            if (accumulate) {
                out[oe * 2 + 0] += o0;
                out[oe * 2 + 1] += o1;
            } else {
                out[oe * 2 + 0] = o0;
                out[oe * 2 + 1] = o1;
            }
        }
    }
}

// ---------------------------------------------------------------- launch
extern "C" void kernel_launch(void* const* d_in, const int* in_sizes, int n_in,
                              void* d_out, int out_size, void* d_ws, size_t ws_size,
                              hipStream_t stream)
{
    const float* h        = (const float*)d_in[0];
    const int*   src      = (const int*)d_in[1];
    const int*   dst      = (const int*)d_in[2];
    const float* emb_w    = (const float*)d_in[3];
    const float* emb_b    = (const float*)d_in[4];
    const float* eps      = (const float*)d_in[5];
    const float* mlp_w1   = (const float*)d_in[6];
    const float* mlp_b1   = (const float*)d_in[7];
    const float* mlp_bn_g = (const float*)d_in[8];
    const float* mlp_bn_b = (const float*)d_in[9];
    const float* mlp_w2   = (const float*)d_in[10];
    const float* mlp_b2   = (const float*)d_in[11];
    const float* app_bn_g = (const float*)d_in[12];
    const float* app_bn_b = (const float*)d_in[13];
    const float* gin_bn_g = (const float*)d_in[14];
    const float* gin_bn_b = (const float*)d_in[15];
    const float* pred_w1  = (const float*)d_in[16];
    const float* pred_b1  = (const float*)d_in[17];
    const float* pred_w2  = (const float*)d_in[18];
    const float* pred_b2  = (const float*)d_in[19];
    float* out = (float*)d_out;

    float* ws   = (float*)d_ws;
    float* x    = ws;                       // [N,128]
    float* tmp1 = ws + NH;                  // [N,128]
    float* tmp2 = ws + 2 * (size_t)NH;      // [N,128]
    float* sums = ws + 3 * (size_t)NH;      // [12][256]
    int*   off  = (int*)(sums + 12 * 256);  // [N]
    int*   deg  = off + NNODES;             // [N]
    int*   epos = deg + NNODES;             // [E]
    unsigned short* eidx = (unsigned short*)(epos + NEDGES); // [E]

    const int NB = NH / 256;                    // 10000
    const int EB = NEDGES / 256;                // 1250
    const int GB = NNODES / ROWS;               // 250
    const int AGB = NNODES * 32 / 256;          // 2500
    const int VB = NH / 2048;                   // 1250
    const int CEB = NNODES / 4;                 // 5000

    // ---- CSR build (graph static across layers)
    hipMemsetAsync(deg, 0, NNODES * sizeof(int), stream);
    hipMemsetAsync(sums, 0, 12 * 256 * sizeof(float), stream);
    k_hist<<<EB, 256, 0, stream>>>(dst, deg);
    k_scan<<<1, 1024, 0, stream>>>(deg, off);
    k_fill<<<EB, 256, 0, stream>>>(src, dst, off, eidx, epos);

    k_embed<<<NB, 256, 0, stream>>>(h, emb_w, emb_b, x);

    // head 0
    k_gemm_head<<<GB, 256, 0, stream>>>(x, pred_w1, pred_b1, tmp1, tmp2);
    k_edge_csr<<<CEB, 256, 0, stream>>>(tmp1, tmp2, off, eidx, epos,
                                        pred_w2, pred_b2, out, 0);

    for (int i = 0; i < NL; ++i) {
        float* s0 = sums + (i * 3 + 0) * 256;
        float* s1 = sums + (i * 3 + 1) * 256;
        float* s2 = sums + (i * 3 + 2) * 256;

        // t = (1+eps)*x + sum_in x[src]
        k_gather<<<AGB, 256, 0, stream>>>(x, off, eidx, eps, i, tmp1);

        // u = t @ W1 + b1 ; stats(u) -> s0
        k_gemm_stat<<<GB, 256, 0, stream>>>(tmp1, mlp_w1 + (size_t)i * HID * HID,
                                            mlp_b1 + i * HID, tmp2, s0);
        // v = relu(BN_s0(u)) @ W2 + b2 ; stats(v) -> s1
        k_gemm_bnin_stat<<<GB, 256, 0, stream>>>(tmp2, s0, mlp_bn_g + i * HID,
                                                 mlp_bn_b + i * HID,
                                                 mlp_w2 + (size_t)i * HID * HID,
                                                 mlp_b2 + i * HID, tmp1, s1);
        // stats(relu(BN_s1(v))) -> s2
        k_app_stat<<<VB, 256, 0, stream>>>(tmp1, s1, app_bn_g + i * HID,
                                           app_bn_b + i * HID, s2);
        // x += relu(BN_s2(relu(BN_s1(v)))) fused into head GEMM staging
        // A -> tmp2, B -> tmp1 (v dead after staging; per-block row ownership)
        k_head_resid<<<GB, 256, 0, stream>>>(tmp1, s1, app_bn_g + i * HID,
                                             app_bn_b + i * HID, s2,
                                             gin_bn_g + i * HID, gin_bn_b + i * HID,
                                             x, pred_w1 + (size_t)(i + 1) * 256 * HID,
                                             pred_b1 + (i + 1) * HID, tmp2, tmp1);
        k_edge_csr<<<CEB, 256, 0, stream>>>(tmp2, tmp1, off, eidx, epos,
                                            pred_w2 + (i + 1) * HID * 2,
                                            pred_b2 + (i + 1) * 2, out, 1);
    }
}

// Round 5
// 828.495 us; speedup vs baseline: 1.5116x; 1.1328x over previous
//
#include <hip/hip_runtime.h>

#define NNODES 20000
#define NEDGES 320000
#define HID 128
#define NL 4

constexpr int NH = NNODES * HID;
#define BN_INV (1.0f / (float)NNODES)
#define XPAD 132
#define ROWS 80          // rows per GEMM block; 20000/80 = 250 blocks
#define RPT 5            // rows per thread (16 row-groups * 5)

typedef unsigned short u16;
typedef unsigned int u32;

// ---------------------------------------------------------------- bf16 utils
__device__ __forceinline__ float bf2f(u32 lo16) {
    union { u32 u; float f; } c; c.u = lo16 << 16; return c.f;
}
__device__ __forceinline__ u16 f2bf(float f) {
    union { float f; u32 u; } c; c.f = f;
    u32 r = c.u + 0x7FFFu + ((c.u >> 16) & 1u);
    return (u16)(r >> 16);
}
__device__ __forceinline__ u32 pack2(float a, float b) {
    return (u32)f2bf(a) | ((u32)f2bf(b) << 16);
}

// ---------------------------------------------------------------- embed
__global__ __launch_bounds__(256) void k_embed(const float* __restrict__ h,
    const float* __restrict__ ew, const float* __restrict__ eb,
    float* __restrict__ x, u16* __restrict__ xh)
{
    int i = blockIdx.x * 256 + threadIdx.x;          // exactly NH threads
    int nrow = i >> 7, j = i & 127;
    float v = fmaf(h[nrow * 2], ew[j], fmaf(h[nrow * 2 + 1], ew[HID + j], eb[j]));
    x[i] = v;
    if (xh) xh[i] = f2bf(v);
}

// ---------------------------------------------------------------- CSR build
__global__ __launch_bounds__(256) void k_hist(const int* __restrict__ dst,
    int* __restrict__ deg)
{
    int e = blockIdx.x * 256 + threadIdx.x;          // exactly NEDGES threads
    atomicAdd(&deg[dst[e]], 1);
}

__global__ __launch_bounds__(1024) void k_scan(const int* __restrict__ deg,
    int* __restrict__ off)
{
    __shared__ int part[1024];
    const int t = threadIdx.x;
    const int lo = t * 20, hi = min(lo + 20, NNODES);
    int s = 0;
    for (int i = lo; i < hi; ++i) s += deg[i];
    part[t] = s;
    __syncthreads();
    for (int d = 1; d < 1024; d <<= 1) {
        int v = (t >= d) ? part[t - d] : 0;
        __syncthreads();
        part[t] += v;
        __syncthreads();
    }
    int base = part[t] - s;                          // exclusive prefix
    for (int i = lo; i < hi; ++i) { off[i] = base; base += deg[i]; }
}

__global__ __launch_bounds__(256) void k_fill(const int* __restrict__ src,
    const int* __restrict__ dst, int* __restrict__ off,
    u16* __restrict__ eidx, int* __restrict__ epos)
{
    int e = blockIdx.x * 256 + threadIdx.x;          // exactly NEDGES threads
    int p = atomicAdd(&off[dst[e]], 1);
    eidx[p] = (u16)src[e];
    epos[p] = e;
}

// ------------------------------------------- pull-mode aggregate (no atomics)
// 16 lanes/node; neighbor rows read from bf16 shadow xh (256B/row).
__global__ __launch_bounds__(256) void k_gather(const float* __restrict__ x,
    const u16* __restrict__ xh, const int* __restrict__ off,
    const u16* __restrict__ eidx, const float* __restrict__ eps, int layer,
    float* __restrict__ t)
{
    int tid = blockIdx.x * 256 + threadIdx.x;        // NNODES*16 threads
    int n = tid >> 4, l = tid & 15;
    int start = (n == 0) ? 0 : off[n - 1];
    int end = off[n];
    const float e1 = 1.0f + eps[layer];
    const float4* xr = reinterpret_cast<const float4*>(x + (size_t)n * HID + l * 8);
    float4 a0 = xr[0], a1 = xr[1];
    float acc[8] = {a0.x * e1, a0.y * e1, a0.z * e1, a0.w * e1,
                    a1.x * e1, a1.y * e1, a1.z * e1, a1.w * e1};
    if (xh) {
        int e = start;
        for (; e + 1 < end; e += 2) {
            const uint4 v0 = *reinterpret_cast<const uint4*>(xh + (size_t)eidx[e] * HID + l * 8);
            const uint4 v1 = *reinterpret_cast<const uint4*>(xh + (size_t)eidx[e + 1] * HID + l * 8);
            acc[0] += bf2f(v0.x & 0xffff) + bf2f(v1.x & 0xffff);
            acc[1] += bf2f(v0.x >> 16)    + bf2f(v1.x >> 16);
            acc[2] += bf2f(v0.y & 0xffff) + bf2f(v1.y & 0xffff);
            acc[3] += bf2f(v0.y >> 16)    + bf2f(v1.y >> 16);
            acc[4] += bf2f(v0.z & 0xffff) + bf2f(v1.z & 0xffff);
            acc[5] += bf2f(v0.z >> 16)    + bf2f(v1.z >> 16);
            acc[6] += bf2f(v0.w & 0xffff) + bf2f(v1.w & 0xffff);
            acc[7] += bf2f(v0.w >> 16)    + bf2f(v1.w >> 16);
        }
        if (e < end) {
            const uint4 v0 = *reinterpret_cast<const uint4*>(xh + (size_t)eidx[e] * HID + l * 8);
            acc[0] += bf2f(v0.x & 0xffff); acc[1] += bf2f(v0.x >> 16);
            acc[2] += bf2f(v0.y & 0xffff); acc[3] += bf2f(v0.y >> 16);
            acc[4] += bf2f(v0.z & 0xffff); acc[5] += bf2f(v0.z >> 16);
            acc[6] += bf2f(v0.w & 0xffff); acc[7] += bf2f(v0.w >> 16);
        }
    } else {
        for (int e = start; e < end; ++e) {
            const float4* vr = reinterpret_cast<const float4*>(x + (size_t)eidx[e] * HID + l * 8);
            float4 v0 = vr[0], v1 = vr[1];
            acc[0] += v0.x; acc[1] += v0.y; acc[2] += v0.z; acc[3] += v0.w;
            acc[4] += v1.x; acc[5] += v1.y; acc[6] += v1.z; acc[7] += v1.w;
        }
    }
    float4* tw = reinterpret_cast<float4*>(t + (size_t)n * HID + l * 8);
    tw[0] = make_float4(acc[0], acc[1], acc[2], acc[3]);
    tw[1] = make_float4(acc[4], acc[5], acc[6], acc[7]);
}

// --------------------------------------------- epilogue stat helper (device)
__device__ __forceinline__ void stat_reduce(float* s8, float* q8, int j0,
    float* ls, float* lq, float* sums)
{
    const int lane = threadIdx.x & 63;
    #pragma unroll
    for (int c = 0; c < 8; ++c) {
        s8[c] += __shfl_xor(s8[c], 16); s8[c] += __shfl_xor(s8[c], 32);
        q8[c] += __shfl_xor(q8[c], 16); q8[c] += __shfl_xor(q8[c], 32);
    }
    if (lane < 16) {
        #pragma unroll
        for (int c = 0; c < 8; ++c) {
            atomicAdd(&ls[j0 + c], s8[c]);
            atomicAdd(&lq[j0 + c], q8[c]);
        }
    }
    __syncthreads();
    if (threadIdx.x < 128) {
        atomicAdd(&sums[threadIdx.x], ls[threadIdx.x]);
        atomicAdd(&sums[128 + threadIdx.x], lq[threadIdx.x]);
    }
}

// ------------------------------------------------------- GEMM + stat epilogue
__global__ __launch_bounds__(256) void k_gemm_stat(const float* __restrict__ X,
    const float* __restrict__ W, const float* __restrict__ bias,
    float* __restrict__ Cm, float* __restrict__ sums)
{
    __shared__ float Xs[ROWS][XPAD];
    __shared__ float ls[128], lq[128];
    const int tid = threadIdx.x;
    const int br = blockIdx.x * ROWS;
    if (tid < 128) { ls[tid] = 0.f; lq[tid] = 0.f; }
    #pragma unroll
    for (int it = 0; it < 10; ++it) {
        int f = tid + it * 256;
        int r = f >> 5, kq = (f & 31) << 2;
        *reinterpret_cast<float4*>(&Xs[r][kq]) =
            *reinterpret_cast<const float4*>(X + (size_t)(br + r) * HID + kq);
    }
    __syncthreads();
    const int j0 = (tid & 15) * 8;
    const int r0 = (tid >> 4) * RPT;
    float acc[RPT][8];
    #pragma unroll
    for (int r = 0; r < RPT; ++r)
        #pragma unroll
        for (int c = 0; c < 8; ++c) acc[r][c] = 0.f;

    for (int k = 0; k < 128; ++k) {
        const float4 wa = *reinterpret_cast<const float4*>(W + k * HID + j0);
        const float4 wb = *reinterpret_cast<const float4*>(W + k * HID + j0 + 4);
        const float w[8] = {wa.x, wa.y, wa.z, wa.w, wb.x, wb.y, wb.z, wb.w};
        #pragma unroll
        for (int r = 0; r < RPT; ++r) {
            const float xv = Xs[r0 + r][k];
            #pragma unroll
            for (int c = 0; c < 8; ++c) acc[r][c] = fmaf(xv, w[c], acc[r][c]);
        }
    }
    float s8[8], q8[8];
    #pragma unroll
    for (int c = 0; c < 8; ++c) { s8[c] = 0.f; q8[c] = 0.f; }
    #pragma unroll
    for (int r = 0; r < RPT; ++r) {
        #pragma unroll
        for (int c = 0; c < 8; ++c) {
            float v = acc[r][c] + bias[j0 + c];
            acc[r][c] = v;
            s8[c] += v;
            q8[c] = fmaf(v, v, q8[c]);
        }
        float* cp = Cm + (size_t)(br + r0 + r) * HID + j0;
        *reinterpret_cast<float4*>(cp)     = make_float4(acc[r][0], acc[r][1], acc[r][2], acc[r][3]);
        *reinterpret_cast<float4*>(cp + 4) = make_float4(acc[r][4], acc[r][5], acc[r][6], acc[r][7]);
    }
    stat_reduce(s8, q8, j0, ls, lq, sums);
}

// Same, but input transformed by BN(sIn,g,b)+ReLU during LDS staging.
__global__ __launch_bounds__(256) void k_gemm_bnin_stat(const float* __restrict__ X,
    const float* __restrict__ sIn, const float* __restrict__ g, const float* __restrict__ b,
    const float* __restrict__ W, const float* __restrict__ bias,
    float* __restrict__ Cm, float* __restrict__ sums)
{
    __shared__ float Xs[ROWS][XPAD];
    __shared__ float ac[256];
    __shared__ float ls[128], lq[128];
    const int tid = threadIdx.x;
    const int br = blockIdx.x * ROWS;
    if (tid < 128) {
        float m = sIn[tid] * BN_INV;
        float var = fmaf(-m, m, sIn[128 + tid] * BN_INV);
        float a = g[tid] * rsqrtf(var + 1e-5f);
        ac[tid] = a;
        ac[128 + tid] = fmaf(-m, a, b[tid]);
        ls[tid] = 0.f; lq[tid] = 0.f;
    }
    __syncthreads();
    #pragma unroll
    for (int it = 0; it < 10; ++it) {
        int f = tid + it * 256;
        int r = f >> 5, kq = (f & 31) << 2;
        float4 v = *reinterpret_cast<const float4*>(X + (size_t)(br + r) * HID + kq);
        v.x = fmaxf(fmaf(ac[kq + 0], v.x, ac[128 + kq + 0]), 0.f);
        v.y = fmaxf(fmaf(ac[kq + 1], v.y, ac[128 + kq + 1]), 0.f);
        v.z = fmaxf(fmaf(ac[kq + 2], v.z, ac[128 + kq + 2]), 0.f);
        v.w = fmaxf(fmaf(ac[kq + 3], v.w, ac[128 + kq + 3]), 0.f);
        *reinterpret_cast<float4*>(&Xs[r][kq]) = v;
    }
    __syncthreads();
    const int j0 = (tid & 15) * 8;
    const int r0 = (tid >> 4) * RPT;
    float acc[RPT][8];
    #pragma unroll
    for (int r = 0; r < RPT; ++r)
        #pragma unroll
        for (int c = 0; c < 8; ++c) acc[r][c] = 0.f;

    for (int k = 0; k < 128; ++k) {
        const float4 wa = *reinterpret_cast<const float4*>(W + k * HID + j0);
        const float4 wb = *reinterpret_cast<const float4*>(W + k * HID + j0 + 4);
        const float w[8] = {wa.x, wa.y, wa.z, wa.w, wb.x, wb.y, wb.z, wb.w};
        #pragma unroll
        for (int r = 0; r < RPT; ++r) {
            const float xv = Xs[r0 + r][k];
            #pragma unroll
            for (int c = 0; c < 8; ++c) acc[r][c] = fmaf(xv, w[c], acc[r][c]);
        }
    }
    float s8[8], q8[8];
    #pragma unroll
    for (int c = 0; c < 8; ++c) { s8[c] = 0.f; q8[c] = 0.f; }
    #pragma unroll
    for (int r = 0; r < RPT; ++r) {
        #pragma unroll
        for (int c = 0; c < 8; ++c) {
            float v = acc[r][c] + bias[j0 + c];
            acc[r][c] = v;
            s8[c] += v;
            q8[c] = fmaf(v, v, q8[c]);
        }
        float* cp = Cm + (size_t)(br + r0 + r) * HID + j0;
        *reinterpret_cast<float4*>(cp)     = make_float4(acc[r][0], acc[r][1], acc[r][2], acc[r][3]);
        *reinterpret_cast<float4*>(cp + 4) = make_float4(acc[r][4], acc[r][5], acc[r][6], acc[r][7]);
    }
    stat_reduce(s8, q8, j0, ls, lq, sums);
}

// --------------------------------- dual-GEMM body -> bf16 A,B outputs
#define HEAD_GEMM_BODY(W1, b1, A, Bm)                                          \
    const int j0 = (tid & 15) * 8;                                             \
    const int r0 = (tid >> 4) * RPT;                                           \
    float accA[RPT][8], accB[RPT][8];                                          \
    _Pragma("unroll")                                                          \
    for (int r = 0; r < RPT; ++r) {                                            \
        _Pragma("unroll")                                                      \
        for (int c = 0; c < 8; ++c) { accA[r][c] = 0.f; accB[r][c] = 0.f; }    \
    }                                                                          \
    for (int k = 0; k < 128; ++k) {                                            \
        const float4 wa0 = *reinterpret_cast<const float4*>(W1 + k * HID + j0);\
        const float4 wa1 = *reinterpret_cast<const float4*>(W1 + k * HID + j0 + 4);\
        const float4 wb0 = *reinterpret_cast<const float4*>(W1 + (HID + k) * HID + j0);\
        const float4 wb1 = *reinterpret_cast<const float4*>(W1 + (HID + k) * HID + j0 + 4);\
        const float wa[8] = {wa0.x, wa0.y, wa0.z, wa0.w, wa1.x, wa1.y, wa1.z, wa1.w};\
        const float wb[8] = {wb0.x, wb0.y, wb0.z, wb0.w, wb1.x, wb1.y, wb1.z, wb1.w};\
        _Pragma("unroll")                                                      \
        for (int r = 0; r < RPT; ++r) {                                        \
            const float xv = Xs[r0 + r][k];                                    \
            _Pragma("unroll")                                                  \
            for (int c = 0; c < 8; ++c) {                                      \
                accA[r][c] = fmaf(xv, wa[c], accA[r][c]);                      \
                accB[r][c] = fmaf(xv, wb[c], accB[r][c]);                      \
            }                                                                  \
        }                                                                      \
    }                                                                          \
    _Pragma("unroll")                                                          \
    for (int r = 0; r < RPT; ++r) {                                            \
        size_t rowoff = (size_t)(br + r0 + r) * HID + j0;                      \
        uint4 av, bv;                                                          \
        av.x = pack2(accA[r][0] + b1[j0 + 0], accA[r][1] + b1[j0 + 1]);        \
        av.y = pack2(accA[r][2] + b1[j0 + 2], accA[r][3] + b1[j0 + 3]);        \
        av.z = pack2(accA[r][4] + b1[j0 + 4], accA[r][5] + b1[j0 + 5]);        \
        av.w = pack2(accA[r][6] + b1[j0 + 6], accA[r][7] + b1[j0 + 7]);        \
        bv.x = pack2(accB[r][0], accB[r][1]);                                  \
        bv.y = pack2(accB[r][2], accB[r][3]);                                  \
        bv.z = pack2(accB[r][4], accB[r][5]);                                  \
        bv.w = pack2(accB[r][6], accB[r][7]);                                  \
        *reinterpret_cast<uint4*>(A + rowoff)  = av;                           \
        *reinterpret_cast<uint4*>(Bm + rowoff) = bv;                           \
    }

// head 0: plain input staging
__global__ __launch_bounds__(256) void k_gemm_head(const float* __restrict__ X,
    const float* __restrict__ W1, const float* __restrict__ b1,
    u16* __restrict__ A, u16* __restrict__ Bm)
{
    __shared__ float Xs[ROWS][XPAD];
    const int tid = threadIdx.x;
    const int br = blockIdx.x * ROWS;
    #pragma unroll
    for (int it = 0; it < 10; ++it) {
        int f = tid + it * 256;
        int r = f >> 5, kq = (f & 31) << 2;
        *reinterpret_cast<float4*>(&Xs[r][kq]) =
            *reinterpret_cast<const float4*>(X + (size_t)(br + r) * HID + kq);
    }
    __syncthreads();
    HEAD_GEMM_BODY(W1, b1, A, Bm)
}

// heads 1..L: staging computes x += relu(gin(relu(app(v)))), writes x (+xh),
// and uses updated x as the GEMM input.
__global__ __launch_bounds__(256) void k_head_resid(const float* __restrict__ v,
    const float* __restrict__ s1, const float* __restrict__ ga, const float* __restrict__ ba,
    const float* __restrict__ s2, const float* __restrict__ gg, const float* __restrict__ bg,
    float* __restrict__ x, u16* __restrict__ xh,
    const float* __restrict__ W1, const float* __restrict__ b1,
    u16* __restrict__ A, u16* __restrict__ Bm)
{
    __shared__ float Xs[ROWS][XPAD];
    __shared__ float aca[256], acg[256];
    const int tid = threadIdx.x;
    const int br = blockIdx.x * ROWS;
    if (tid < 128) {
        float m = s1[tid] * BN_INV;
        float var = fmaf(-m, m, s1[128 + tid] * BN_INV);
        float a = ga[tid] * rsqrtf(var + 1e-5f);
        aca[tid] = a;
        aca[128 + tid] = fmaf(-m, a, ba[tid]);
        float m2 = s2[tid] * BN_INV;
        float var2 = fmaf(-m2, m2, s2[128 + tid] * BN_INV);
        float a2 = gg[tid] * rsqrtf(var2 + 1e-5f);
        acg[tid] = a2;
        acg[128 + tid] = fmaf(-m2, a2, bg[tid]);
    }
    __syncthreads();
    #pragma unroll
    for (int it = 0; it < 10; ++it) {
        int f = tid + it * 256;
        int r = f >> 5, kq = (f & 31) << 2;
        size_t goff = (size_t)(br + r) * HID + kq;
        float4 vv = *reinterpret_cast<const float4*>(v + goff);
        float4 xv = *reinterpret_cast<const float4*>(x + goff);
        float t0 = fmaxf(fmaf(aca[kq + 0], vv.x, aca[128 + kq + 0]), 0.f);
        float t1 = fmaxf(fmaf(aca[kq + 1], vv.y, aca[128 + kq + 1]), 0.f);
        float t2 = fmaxf(fmaf(aca[kq + 2], vv.z, aca[128 + kq + 2]), 0.f);
        float t3 = fmaxf(fmaf(aca[kq + 3], vv.w, aca[128 + kq + 3]), 0.f);
        xv.x += fmaxf(fmaf(acg[kq + 0], t0, acg[128 + kq + 0]), 0.f);
        xv.y += fmaxf(fmaf(acg[kq + 1], t1, acg[128 + kq + 1]), 0.f);
        xv.z += fmaxf(fmaf(acg[kq + 2], t2, acg[128 + kq + 2]), 0.f);
        xv.w += fmaxf(fmaf(acg[kq + 3], t3, acg[128 + kq + 3]), 0.f);
        *reinterpret_cast<float4*>(x + goff) = xv;
        if (xh) *reinterpret_cast<uint2*>(xh + goff) =
            make_uint2(pack2(xv.x, xv.y), pack2(xv.z, xv.w));
        *reinterpret_cast<float4*>(&Xs[r][kq]) = xv;
    }
    __syncthreads();
    HEAD_GEMM_BODY(W1, b1, A, Bm)
}

// ------------------------------------- stats of relu(app(v)) -> s2
__global__ __launch_bounds__(256) void k_app_stat(const float* __restrict__ v,
    const float* __restrict__ s1, const float* __restrict__ g, const float* __restrict__ b,
    float* __restrict__ s2)
{
    __shared__ float ac[256];
    __shared__ float ls[128], lq[128];
    const int tid = threadIdx.x;
    if (tid < 128) {
        float m = s1[tid] * BN_INV;
        float var = fmaf(-m, m, s1[128 + tid] * BN_INV);
        float a = g[tid] * rsqrtf(var + 1e-5f);
        ac[tid] = a;
        ac[128 + tid] = fmaf(-m, a, b[tid]);
        ls[tid] = 0.f; lq[tid] = 0.f;
    }
    __syncthreads();
    const size_t base = (size_t)blockIdx.x * 2048 + tid * 8;   // grid 1250
    const int j0 = (tid & 15) * 8;
    float4 v0 = *reinterpret_cast<const float4*>(v + base);
    float4 v1 = *reinterpret_cast<const float4*>(v + base + 4);
    float w[8] = {v0.x, v0.y, v0.z, v0.w, v1.x, v1.y, v1.z, v1.w};
    float s8[8], q8[8];
    #pragma unroll
    for (int c = 0; c < 8; ++c) {
        w[c] = fmaxf(fmaf(ac[j0 + c], w[c], ac[128 + j0 + c]), 0.f);
        s8[c] = w[c];
        q8[c] = w[c] * w[c];
    }
    stat_reduce(s8, q8, j0, ls, lq, s2);
}

// ---------------------------------------------------- edge head (dst-CSR)
// wave = 1 dst node; 16 lanes/edge (uint4 = 8 bf16), 4 edges in flight.
__global__ __launch_bounds__(256) void k_edge_csr(const u16* __restrict__ Ah,
    const u16* __restrict__ Bh, const int* __restrict__ off,
    const u16* __restrict__ eidx, const int* __restrict__ epos,
    const float* __restrict__ w2, const float* __restrict__ b2,
    float* __restrict__ out, int accumulate)
{
    const int wid = (blockIdx.x * 256 + threadIdx.x) >> 6;   // node; grid 5000
    const int lane = threadIdx.x & 63;
    const int q = lane >> 4, l = lane & 15;
    const int start = wid ? off[wid - 1] : 0;
    const int end = off[wid];
    const uint4 bb = *reinterpret_cast<const uint4*>(Bh + (size_t)wid * HID + l * 8);
    float b8[8] = {bf2f(bb.x & 0xffff), bf2f(bb.x >> 16),
                   bf2f(bb.y & 0xffff), bf2f(bb.y >> 16),
                   bf2f(bb.z & 0xffff), bf2f(bb.z >> 16),
                   bf2f(bb.w & 0xffff), bf2f(bb.w >> 16)};
    float w2f[16];
    #pragma unroll
    for (int t = 0; t < 4; ++t)
        *reinterpret_cast<float4*>(&w2f[t * 4]) =
            *reinterpret_cast<const float4*>(w2 + l * 16 + t * 4);
    const float bias0 = b2[0], bias1 = b2[1];
    for (int e = start + q; e < end; e += 4) {
        int s = eidx[e];
        const uint4 aa = *reinterpret_cast<const uint4*>(Ah + (size_t)s * HID + l * 8);
        float a8[8] = {bf2f(aa.x & 0xffff), bf2f(aa.x >> 16),
                       bf2f(aa.y & 0xffff), bf2f(aa.y >> 16),
                       bf2f(aa.z & 0xffff), bf2f(aa.z >> 16),
                       bf2f(aa.w & 0xffff), bf2f(aa.w >> 16)};
        float s0 = 0.f, s1 = 0.f;
        #pragma unroll
        for (int j = 0; j < 8; ++j) {
            float z = fmaxf(a8[j] + b8[j], 0.f);
            s0 = fmaf(z, w2f[j * 2], s0);
            s1 = fmaf(z, w2f[j * 2 + 1], s1);
        }
        #pragma unroll
        for (int m = 8; m >= 1; m >>= 1) {
            s0 += __shfl_xor(s0, m);
            s1 += __shfl_xor(s1, m);
        }
        if (l == 0) {
            int oe = epos[e];
            float o0 = s0 + bias0, o1 = s1 + bias1;
            if (accumulate) {
                out[oe * 2 + 0] += o0;
                out[oe * 2 + 1] += o1;
            } else {
                out[oe * 2 + 0] = o0;
                out[oe * 2 + 1] = o1;
            }
        }
    }
}

// ---------------------------------------------------------------- launch
extern "C" void kernel_launch(void* const* d_in, const int* in_sizes, int n_in,
                              void* d_out, int out_size, void* d_ws, size_t ws_size,
                              hipStream_t stream)
{
    const float* h        = (const float*)d_in[0];
    const int*   src      = (const int*)d_in[1];
    const int*   dst      = (const int*)d_in[2];
    const float* emb_w    = (const float*)d_in[3];
    const float* emb_b    = (const float*)d_in[4];
    const float* eps      = (const float*)d_in[5];
    const float* mlp_w1   = (const float*)d_in[6];
    const float* mlp_b1   = (const float*)d_in[7];
    const float* mlp_bn_g = (const float*)d_in[8];
    const float* mlp_bn_b = (const float*)d_in[9];
    const float* mlp_w2   = (const float*)d_in[10];
    const float* mlp_b2   = (const float*)d_in[11];
    const float* app_bn_g = (const float*)d_in[12];
    const float* app_bn_b = (const float*)d_in[13];
    const float* gin_bn_g = (const float*)d_in[14];
    const float* gin_bn_b = (const float*)d_in[15];
    const float* pred_w1  = (const float*)d_in[16];
    const float* pred_b1  = (const float*)d_in[17];
    const float* pred_w2  = (const float*)d_in[18];
    const float* pred_b2  = (const float*)d_in[19];
    float* out = (float*)d_out;

    float* ws   = (float*)d_ws;
    float* x    = ws;                       // [N,128] f32
    float* tmp1 = ws + NH;                  // [N,128] f32
    float* tmp2 = ws + 2 * (size_t)NH;      // [N,128] f32, aliased by bf16 A,B
    float* sums = ws + 3 * (size_t)NH;      // [12][256]
    int*   off  = (int*)(sums + 12 * 256);  // [N]
    int*   deg  = off + NNODES;             // [N]
    int*   epos = deg + NNODES;             // [E]
    u16*   eidx = (u16*)(epos + NEDGES);    // [E]
    u16*   ah   = (u16*)tmp2;               // [N,128] bf16 (aliases tmp2 low half)
    u16*   bh   = ah + NH;                  // [N,128] bf16 (aliases tmp2 high half)
    // optional bf16 shadow of x, placed after eidx if workspace allows
    size_t used_bytes = ((size_t)3 * NH + 12 * 256) * 4 + 2ull * NNODES * 4
                        + (size_t)NEDGES * 4 + (size_t)NEDGES * 2;
    u16* xh = (used_bytes + (size_t)NH * 2 <= ws_size) ? (eidx + NEDGES) : nullptr;

    const int NB = NH / 256;                    // 10000
    const int EB = NEDGES / 256;                // 1250
    const int GB = NNODES / ROWS;               // 250
    const int AGB = NNODES * 16 / 256;          // 1250
    const int VB = NH / 2048;                   // 1250
    const int CEB = NNODES / 4;                 // 5000

    // ---- CSR build (graph static across layers)
    hipMemsetAsync(deg, 0, NNODES * sizeof(int), stream);
    hipMemsetAsync(sums, 0, 12 * 256 * sizeof(float), stream);
    k_hist<<<EB, 256, 0, stream>>>(dst, deg);
    k_scan<<<1, 1024, 0, stream>>>(deg, off);
    k_fill<<<EB, 256, 0, stream>>>(src, dst, off, eidx, epos);

    k_embed<<<NB, 256, 0, stream>>>(h, emb_w, emb_b, x, xh);

    // head 0
    k_gemm_head<<<GB, 256, 0, stream>>>(x, pred_w1, pred_b1, ah, bh);
    k_edge_csr<<<CEB, 256, 0, stream>>>(ah, bh, off, eidx, epos,
                                        pred_w2, pred_b2, out, 0);

    for (int i = 0; i < NL; ++i) {
        float* s0 = sums + (i * 3 + 0) * 256;
        float* s1 = sums + (i * 3 + 1) * 256;
        float* s2 = sums + (i * 3 + 2) * 256;

        // t = (1+eps)*x + sum_in x[src]  (bf16 neighbor reads)
        k_gather<<<AGB, 256, 0, stream>>>(x, xh, off, eidx, eps, i, tmp1);

        // u = t @ W1 + b1 ; stats(u) -> s0
        k_gemm_stat<<<GB, 256, 0, stream>>>(tmp1, mlp_w1 + (size_t)i * HID * HID,
                                            mlp_b1 + i * HID, tmp2, s0);
        // v = relu(BN_s0(u)) @ W2 + b2 ; stats(v) -> s1
        k_gemm_bnin_stat<<<GB, 256, 0, stream>>>(tmp2, s0, mlp_bn_g + i * HID,
                                                 mlp_bn_b + i * HID,
                                                 mlp_w2 + (size_t)i * HID * HID,
                                                 mlp_b2 + i * HID, tmp1, s1);
        // stats(relu(BN_s1(v))) -> s2
        k_app_stat<<<VB, 256, 0, stream>>>(tmp1, s1, app_bn_g + i * HID,
                                           app_bn_b + i * HID, s2);
        // x += relu(BN_s2(relu(BN_s1(v)))) fused into head GEMM staging;
        // A,B (bf16) overwrite tmp2 (u is dead). Per-block row ownership.
        k_head_resid<<<GB, 256, 0, stream>>>(tmp1, s1, app_bn_g + i * HID,
                                             app_bn_b + i * HID, s2,
                                             gin_bn_g + i * HID, gin_bn_b + i * HID,
                                             x, xh,
                                             pred_w1 + (size_t)(i + 1) * 256 * HID,
                                             pred_b1 + (i + 1) * HID, ah, bh);
        k_edge_csr<<<CEB, 256, 0, stream>>>(ah, bh, off, eidx, epos,
                                            pred_w2 + (i + 1) * HID * 2,
                                            pred_b2 + (i + 1) * 2, out, 1);
    }
}

// Round 7
// 797.067 us; speedup vs baseline: 1.5712x; 1.0394x over previous
//
#include <hip/hip_runtime.h>

#define NNODES 20000
#define NEDGES 320000
#define HID 128
#define NL 4

constexpr int NH = NNODES * HID;
#define BN_INV (1.0f / (float)NNODES)
#define XPAD 132
#define ROWS 40          // rows per GEMM block; 20000/40 = 500 blocks (2/CU)
#define RPT 5            // rows per thread: 8 row-groups * 5
// thread tile: 5 rows x 4 cols; 32 col-groups (tid&31) x 8 row-groups (tid>>5)

typedef unsigned short u16;
typedef unsigned int u32;

// ---------------------------------------------------------------- bf16 utils
__device__ __forceinline__ float bf2f(u32 lo16) {
    union { u32 u; float f; } c; c.u = lo16 << 16; return c.f;
}
__device__ __forceinline__ u16 f2bf(float f) {
    union { float f; u32 u; } c; c.f = f;
    u32 r = c.u + 0x7FFFu + ((c.u >> 16) & 1u);
    return (u16)(r >> 16);
}
__device__ __forceinline__ u32 pack2(float a, float b) {
    return (u32)f2bf(a) | ((u32)f2bf(b) << 16);
}

// ---------------------------------------------------------------- embed
__global__ __launch_bounds__(256) void k_embed(const float* __restrict__ h,
    const float* __restrict__ ew, const float* __restrict__ eb,
    float* __restrict__ x, u16* __restrict__ xh)
{
    int i = blockIdx.x * 256 + threadIdx.x;          // exactly NH threads
    int nrow = i >> 7, j = i & 127;
    float v = fmaf(h[nrow * 2], ew[j], fmaf(h[nrow * 2 + 1], ew[HID + j], eb[j]));
    x[i] = v;
    if (xh) xh[i] = f2bf(v);
}

// ---------------------------------------------------------------- CSR build
__global__ __launch_bounds__(256) void k_hist(const int* __restrict__ dst,
    int* __restrict__ deg)
{
    int e = blockIdx.x * 256 + threadIdx.x;          // exactly NEDGES threads
    atomicAdd(&deg[dst[e]], 1);
}

__global__ __launch_bounds__(1024) void k_scan(const int* __restrict__ deg,
    int* __restrict__ off)
{
    __shared__ int part[1024];
    const int t = threadIdx.x;
    const int lo = t * 20, hi = min(lo + 20, NNODES);
    int s = 0;
    for (int i = lo; i < hi; ++i) s += deg[i];
    part[t] = s;
    __syncthreads();
    for (int d = 1; d < 1024; d <<= 1) {
        int v = (t >= d) ? part[t - d] : 0;
        __syncthreads();
        part[t] += v;
        __syncthreads();
    }
    int base = part[t] - s;                          // exclusive prefix
    for (int i = lo; i < hi; ++i) { off[i] = base; base += deg[i]; }
}

__global__ __launch_bounds__(256) void k_fill(const int* __restrict__ src,
    const int* __restrict__ dst, int* __restrict__ off,
    u16* __restrict__ eidx, int* __restrict__ epos)
{
    int e = blockIdx.x * 256 + threadIdx.x;          // exactly NEDGES threads
    int p = atomicAdd(&off[dst[e]], 1);
    eidx[p] = (u16)src[e];
    epos[p] = e;
}

// ------------------------------------------- pull-mode aggregate (no atomics)
__global__ __launch_bounds__(256) void k_gather(const float* __restrict__ x,
    const u16* __restrict__ xh, const int* __restrict__ off,
    const u16* __restrict__ eidx, const float* __restrict__ eps, int layer,
    float* __restrict__ t)
{
    int tid = blockIdx.x * 256 + threadIdx.x;        // NNODES*16 threads
    int n = tid >> 4, l = tid & 15;
    int start = (n == 0) ? 0 : off[n - 1];
    int end = off[n];
    const float e1 = 1.0f + eps[layer];
    const float4* xr = reinterpret_cast<const float4*>(x + (size_t)n * HID + l * 8);
    float4 a0 = xr[0], a1 = xr[1];
    float acc[8] = {a0.x * e1, a0.y * e1, a0.z * e1, a0.w * e1,
                    a1.x * e1, a1.y * e1, a1.z * e1, a1.w * e1};
    if (xh) {
        int e = start;
        for (; e + 1 < end; e += 2) {
            const uint4 v0 = *reinterpret_cast<const uint4*>(xh + (size_t)eidx[e] * HID + l * 8);
            const uint4 v1 = *reinterpret_cast<const uint4*>(xh + (size_t)eidx[e + 1] * HID + l * 8);
            acc[0] += bf2f(v0.x & 0xffff) + bf2f(v1.x & 0xffff);
            acc[1] += bf2f(v0.x >> 16)    + bf2f(v1.x >> 16);
            acc[2] += bf2f(v0.y & 0xffff) + bf2f(v1.y & 0xffff);
            acc[3] += bf2f(v0.y >> 16)    + bf2f(v1.y >> 16);
            acc[4] += bf2f(v0.z & 0xffff) + bf2f(v1.z & 0xffff);
            acc[5] += bf2f(v0.z >> 16)    + bf2f(v1.z >> 16);
            acc[6] += bf2f(v0.w & 0xffff) + bf2f(v1.w & 0xffff);
            acc[7] += bf2f(v0.w >> 16)    + bf2f(v1.w >> 16);
        }
        if (e < end) {
            const uint4 v0 = *reinterpret_cast<const uint4*>(xh + (size_t)eidx[e] * HID + l * 8);
            acc[0] += bf2f(v0.x & 0xffff); acc[1] += bf2f(v0.x >> 16);
            acc[2] += bf2f(v0.y & 0xffff); acc[3] += bf2f(v0.y >> 16);
            acc[4] += bf2f(v0.z & 0xffff); acc[5] += bf2f(v0.z >> 16);
            acc[6] += bf2f(v0.w & 0xffff); acc[7] += bf2f(v0.w >> 16);
        }
    } else {
        for (int e = start; e < end; ++e) {
            const float4* vr = reinterpret_cast<const float4*>(x + (size_t)eidx[e] * HID + l * 8);
            float4 v0 = vr[0], v1 = vr[1];
            acc[0] += v0.x; acc[1] += v0.y; acc[2] += v0.z; acc[3] += v0.w;
            acc[4] += v1.x; acc[5] += v1.y; acc[6] += v1.z; acc[7] += v1.w;
        }
    }
    float4* tw = reinterpret_cast<float4*>(t + (size_t)n * HID + l * 8);
    tw[0] = make_float4(acc[0], acc[1], acc[2], acc[3]);
    tw[1] = make_float4(acc[4], acc[5], acc[6], acc[7]);
}

// --------------------------------------------- epilogue stat helper (device)
// thread tile 4 cols at j0=(tid&31)*4; lane^32 pairs same j0, then LDS+global
__device__ __forceinline__ void stat_reduce4(float* s4, float* q4, int j0,
    float* ls, float* lq, float* sums)
{
    const int lane = threadIdx.x & 63;
    #pragma unroll
    for (int c = 0; c < 4; ++c) {
        s4[c] += __shfl_xor(s4[c], 32);
        q4[c] += __shfl_xor(q4[c], 32);
    }
    if (lane < 32) {
        #pragma unroll
        for (int c = 0; c < 4; ++c) {
            atomicAdd(&ls[j0 + c], s4[c]);
            atomicAdd(&lq[j0 + c], q4[c]);
        }
    }
    __syncthreads();
    if (threadIdx.x < 128) {
        atomicAdd(&sums[threadIdx.x], ls[threadIdx.x]);
        atomicAdd(&sums[128 + threadIdx.x], lq[threadIdx.x]);
    }
}

// ------------------------------------------------------- GEMM + stat epilogue
// C[N,128] = X@W + bias ; BN partial sums into sums[256]. 40 rows/block.
__global__ __launch_bounds__(256) void k_gemm_stat(const float* __restrict__ X,
    const float* __restrict__ W, const float* __restrict__ bias,
    float* __restrict__ Cm, float* __restrict__ sums)
{
    __shared__ float Xs[ROWS][XPAD];
    __shared__ float ls[128], lq[128];
    const int tid = threadIdx.x;
    const int br = blockIdx.x * ROWS;
    if (tid < 128) { ls[tid] = 0.f; lq[tid] = 0.f; }
    #pragma unroll
    for (int it = 0; it < 5; ++it) {
        int f = tid + it * 256;
        int r = f >> 5, kq = (f & 31) << 2;
        *reinterpret_cast<float4*>(&Xs[r][kq]) =
            *reinterpret_cast<const float4*>(X + (size_t)(br + r) * HID + kq);
    }
    __syncthreads();
    const int j0 = (tid & 31) * 4;
    const int r0 = (tid >> 5) * RPT;
    float acc[RPT][4];
    #pragma unroll
    for (int r = 0; r < RPT; ++r)
        #pragma unroll
        for (int c = 0; c < 4; ++c) acc[r][c] = 0.f;

    #pragma unroll 4
    for (int k = 0; k < 128; ++k) {
        const float4 w4 = *reinterpret_cast<const float4*>(W + k * HID + j0);
        #pragma unroll
        for (int r = 0; r < RPT; ++r) {
            const float xv = Xs[r0 + r][k];
            acc[r][0] = fmaf(xv, w4.x, acc[r][0]);
            acc[r][1] = fmaf(xv, w4.y, acc[r][1]);
            acc[r][2] = fmaf(xv, w4.z, acc[r][2]);
            acc[r][3] = fmaf(xv, w4.w, acc[r][3]);
        }
    }
    const float4 bv = *reinterpret_cast<const float4*>(bias + j0);
    const float b4[4] = {bv.x, bv.y, bv.z, bv.w};
    float s4[4] = {0.f, 0.f, 0.f, 0.f}, q4[4] = {0.f, 0.f, 0.f, 0.f};
    #pragma unroll
    for (int r = 0; r < RPT; ++r) {
        #pragma unroll
        for (int c = 0; c < 4; ++c) {
            float v = acc[r][c] + b4[c];
            acc[r][c] = v;
            s4[c] += v;
            q4[c] = fmaf(v, v, q4[c]);
        }
        *reinterpret_cast<float4*>(Cm + (size_t)(br + r0 + r) * HID + j0) =
            make_float4(acc[r][0], acc[r][1], acc[r][2], acc[r][3]);
    }
    stat_reduce4(s4, q4, j0, ls, lq, sums);
}

// Same, but input transformed by BN(sIn,g,b)+ReLU during LDS staging.
__global__ __launch_bounds__(256) void k_gemm_bnin_stat(const float* __restrict__ X,
    const float* __restrict__ sIn, const float* __restrict__ g, const float* __restrict__ b,
    const float* __restrict__ W, const float* __restrict__ bias,
    float* __restrict__ Cm, float* __restrict__ sums)
{
    __shared__ float Xs[ROWS][XPAD];
    __shared__ float ac[256];
    __shared__ float ls[128], lq[128];
    const int tid = threadIdx.x;
    const int br = blockIdx.x * ROWS;
    if (tid < 128) {
        float m = sIn[tid] * BN_INV;
        float var = fmaf(-m, m, sIn[128 + tid] * BN_INV);
        float a = g[tid] * rsqrtf(var + 1e-5f);
        ac[tid] = a;
        ac[128 + tid] = fmaf(-m, a, b[tid]);
        ls[tid] = 0.f; lq[tid] = 0.f;
    }
    __syncthreads();
    #pragma unroll
    for (int it = 0; it < 5; ++it) {
        int f = tid + it * 256;
        int r = f >> 5, kq = (f & 31) << 2;
        float4 v = *reinterpret_cast<const float4*>(X + (size_t)(br + r) * HID + kq);
        v.x = fmaxf(fmaf(ac[kq + 0], v.x, ac[128 + kq + 0]), 0.f);
        v.y = fmaxf(fmaf(ac[kq + 1], v.y, ac[128 + kq + 1]), 0.f);
        v.z = fmaxf(fmaf(ac[kq + 2], v.z, ac[128 + kq + 2]), 0.f);
        v.w = fmaxf(fmaf(ac[kq + 3], v.w, ac[128 + kq + 3]), 0.f);
        *reinterpret_cast<float4*>(&Xs[r][kq]) = v;
    }
    __syncthreads();
    const int j0 = (tid & 31) * 4;
    const int r0 = (tid >> 5) * RPT;
    float acc[RPT][4];
    #pragma unroll
    for (int r = 0; r < RPT; ++r)
        #pragma unroll
        for (int c = 0; c < 4; ++c) acc[r][c] = 0.f;

    #pragma unroll 4
    for (int k = 0; k < 128; ++k) {
        const float4 w4 = *reinterpret_cast<const float4*>(W + k * HID + j0);
        #pragma unroll
        for (int r = 0; r < RPT; ++r) {
            const float xv = Xs[r0 + r][k];
            acc[r][0] = fmaf(xv, w4.x, acc[r][0]);
            acc[r][1] = fmaf(xv, w4.y, acc[r][1]);
            acc[r][2] = fmaf(xv, w4.z, acc[r][2]);
            acc[r][3] = fmaf(xv, w4.w, acc[r][3]);
        }
    }
    const float4 bv = *reinterpret_cast<const float4*>(bias + j0);
    const float b4[4] = {bv.x, bv.y, bv.z, bv.w};
    float s4[4] = {0.f, 0.f, 0.f, 0.f}, q4[4] = {0.f, 0.f, 0.f, 0.f};
    #pragma unroll
    for (int r = 0; r < RPT; ++r) {
        #pragma unroll
        for (int c = 0; c < 4; ++c) {
            float v = acc[r][c] + b4[c];
            acc[r][c] = v;
            s4[c] += v;
            q4[c] = fmaf(v, v, q4[c]);
        }
        *reinterpret_cast<float4*>(Cm + (size_t)(br + r0 + r) * HID + j0) =
            make_float4(acc[r][0], acc[r][1], acc[r][2], acc[r][3]);
    }
    stat_reduce4(s4, q4, j0, ls, lq, sums);
}

// --------------------------------- dual-GEMM body -> bf16 A,B outputs
#define HEAD_GEMM_BODY(W1, b1, A, Bm)                                          \
    const int j0 = (tid & 31) * 4;                                             \
    const int r0 = (tid >> 5) * RPT;                                           \
    float accA[RPT][4], accB[RPT][4];                                          \
    _Pragma("unroll")                                                          \
    for (int r = 0; r < RPT; ++r) {                                            \
        _Pragma("unroll")                                                      \
        for (int c = 0; c < 4; ++c) { accA[r][c] = 0.f; accB[r][c] = 0.f; }    \
    }                                                                          \
    _Pragma("unroll 4")                                                        \
    for (int k = 0; k < 128; ++k) {                                            \
        const float4 wa = *reinterpret_cast<const float4*>(W1 + k * HID + j0); \
        const float4 wb = *reinterpret_cast<const float4*>(W1 + (HID + k) * HID + j0);\
        _Pragma("unroll")                                                      \
        for (int r = 0; r < RPT; ++r) {                                        \
            const float xv = Xs[r0 + r][k];                                    \
            accA[r][0] = fmaf(xv, wa.x, accA[r][0]);                           \
            accA[r][1] = fmaf(xv, wa.y, accA[r][1]);                           \
            accA[r][2] = fmaf(xv, wa.z, accA[r][2]);                           \
            accA[r][3] = fmaf(xv, wa.w, accA[r][3]);                           \
            accB[r][0] = fmaf(xv, wb.x, accB[r][0]);                           \
            accB[r][1] = fmaf(xv, wb.y, accB[r][1]);                           \
            accB[r][2] = fmaf(xv, wb.z, accB[r][2]);                           \
            accB[r][3] = fmaf(xv, wb.w, accB[r][3]);                           \
        }                                                                      \
    }                                                                          \
    const float4 bv1 = *reinterpret_cast<const float4*>(b1 + j0);              \
    _Pragma("unroll")                                                          \
    for (int r = 0; r < RPT; ++r) {                                            \
        size_t rowoff = (size_t)(br + r0 + r) * HID + j0;                      \
        uint2 av, bvv;                                                         \
        av.x = pack2(accA[r][0] + bv1.x, accA[r][1] + bv1.y);                  \
        av.y = pack2(accA[r][2] + bv1.z, accA[r][3] + bv1.w);                  \
        bvv.x = pack2(accB[r][0], accB[r][1]);                                 \
        bvv.y = pack2(accB[r][2], accB[r][3]);                                 \
        *reinterpret_cast<uint2*>(A + rowoff)  = av;                           \
        *reinterpret_cast<uint2*>(Bm + rowoff) = bvv;                          \
    }

// head 0: plain input staging
__global__ __launch_bounds__(256) void k_gemm_head(const float* __restrict__ X,
    const float* __restrict__ W1, const float* __restrict__ b1,
    u16* __restrict__ A, u16* __restrict__ Bm)
{
    __shared__ float Xs[ROWS][XPAD];
    const int tid = threadIdx.x;
    const int br = blockIdx.x * ROWS;
    #pragma unroll
    for (int it = 0; it < 5; ++it) {
        int f = tid + it * 256;
        int r = f >> 5, kq = (f & 31) << 2;
        *reinterpret_cast<float4*>(&Xs[r][kq]) =
            *reinterpret_cast<const float4*>(X + (size_t)(br + r) * HID + kq);
    }
    __syncthreads();
    HEAD_GEMM_BODY(W1, b1, A, Bm)
}

// heads 1..L: staging computes x += relu(gin(relu(app(v)))), writes x (+xh),
// and uses updated x as the GEMM input.
__global__ __launch_bounds__(256) void k_head_resid(const float* __restrict__ v,
    const float* __restrict__ s1, const float* __restrict__ ga, const float* __restrict__ ba,
    const float* __restrict__ s2, const float* __restrict__ gg, const float* __restrict__ bg,
    float* __restrict__ x, u16* __restrict__ xh,
    const float* __restrict__ W1, const float* __restrict__ b1,
    u16* __restrict__ A, u16* __restrict__ Bm)
{
    __shared__ float Xs[ROWS][XPAD];
    __shared__ float aca[256], acg[256];
    const int tid = threadIdx.x;
    const int br = blockIdx.x * ROWS;
    if (tid < 128) {
        float m = s1[tid] * BN_INV;
        float var = fmaf(-m, m, s1[128 + tid] * BN_INV);
        float a = ga[tid] * rsqrtf(var + 1e-5f);
        aca[tid] = a;
        aca[128 + tid] = fmaf(-m, a, ba[tid]);
        float m2 = s2[tid] * BN_INV;
        float var2 = fmaf(-m2, m2, s2[128 + tid] * BN_INV);
        float a2 = gg[tid] * rsqrtf(var2 + 1e-5f);
        acg[tid] = a2;
        acg[128 + tid] = fmaf(-m2, a2, bg[tid]);
    }
    __syncthreads();
    #pragma unroll
    for (int it = 0; it < 5; ++it) {
        int f = tid + it * 256;
        int r = f >> 5, kq = (f & 31) << 2;
        size_t goff = (size_t)(br + r) * HID + kq;
        float4 vv = *reinterpret_cast<const float4*>(v + goff);
        float4 xv = *reinterpret_cast<const float4*>(x + goff);
        float t0 = fmaxf(fmaf(aca[kq + 0], vv.x, aca[128 + kq + 0]), 0.f);
        float t1 = fmaxf(fmaf(aca[kq + 1], vv.y, aca[128 + kq + 1]), 0.f);
        float t2 = fmaxf(fmaf(aca[kq + 2], vv.z, aca[128 + kq + 2]), 0.f);
        float t3 = fmaxf(fmaf(aca[kq + 3], vv.w, aca[128 + kq + 3]), 0.f);
        xv.x += fmaxf(fmaf(acg[kq + 0], t0, acg[128 + kq + 0]), 0.f);
        xv.y += fmaxf(fmaf(acg[kq + 1], t1, acg[128 + kq + 1]), 0.f);
        xv.z += fmaxf(fmaf(acg[kq + 2], t2, acg[128 + kq + 2]), 0.f);
        xv.w += fmaxf(fmaf(acg[kq + 3], t3, acg[128 + kq + 3]), 0.f);
        *reinterpret_cast<float4*>(x + goff) = xv;
        if (xh) *reinterpret_cast<uint2*>(xh + goff) =
            make_uint2(pack2(xv.x, xv.y), pack2(xv.z, xv.w));
        *reinterpret_cast<float4*>(&Xs[r][kq]) = xv;
    }
    __syncthreads();
    HEAD_GEMM_BODY(W1, b1, A, Bm)
}

// ------------------------------------- stats of relu(app(v)) -> s2
// grid 1250 blocks x 16 rows: thread handles rows row0 and row0+8, 4 cols.
__global__ __launch_bounds__(256) void k_app_stat(const float* __restrict__ v,
    const float* __restrict__ s1, const float* __restrict__ g, const float* __restrict__ b,
    float* __restrict__ s2)
{
    __shared__ float ac[256];
    __shared__ float ls[128], lq[128];
    const int tid = threadIdx.x;
    if (tid < 128) {
        float m = s1[tid] * BN_INV;
        float var = fmaf(-m, m, s1[128 + tid] * BN_INV);
        float a = g[tid] * rsqrtf(var + 1e-5f);
        ac[tid] = a;
        ac[128 + tid] = fmaf(-m, a, b[tid]);
        ls[tid] = 0.f; lq[tid] = 0.f;
    }
    __syncthreads();
    const int j0 = (tid & 31) * 4;
    const int row0 = blockIdx.x * 16 + (tid >> 5);   // rows row0, row0+8
    float s4[4] = {0.f, 0.f, 0.f, 0.f}, q4[4] = {0.f, 0.f, 0.f, 0.f};
    #pragma unroll
    for (int rr = 0; rr < 2; ++rr) {
        const float4 v4 = *reinterpret_cast<const float4*>(
            v + (size_t)(row0 + rr * 8) * HID + j0);
        float w[4] = {v4.x, v4.y, v4.z, v4.w};
        #pragma unroll
        for (int c = 0; c < 4; ++c) {
            w[c] = fmaxf(fmaf(ac[j0 + c], w[c], ac[128 + j0 + c]), 0.f);
            s4[c] += w[c];
            q4[c] = fmaf(w[c], w[c], q4[c]);
        }
    }
    stat_reduce4(s4, q4, j0, ls, lq, s2);
}

// ---------------------------------------------------- edge head (dst-CSR)
// wave = 1 dst node; 16 lanes/edge (uint4 = 8 bf16), 4 edges in flight.
__global__ __launch_bounds__(256) void k_edge_csr(const u16* __restrict__ Ah,
    const u16* __restrict__ Bh, const int* __restrict__ off,
    const u16* __restrict__ eidx, const int* __restrict__ epos,
    const float* __restrict__ w2, const float* __restrict__ b2,
    float* __restrict__ out, int accumulate)
{
    const int wid = (blockIdx.x * 256 + threadIdx.x) >> 6;   // node; grid 5000
    const int lane = threadIdx.x & 63;
    const int q = lane >> 4, l = lane & 15;
    const int start = wid ? off[wid - 1] : 0;
    const int end = off[wid];
    const uint4 bb = *reinterpret_cast<const uint4*>(Bh + (size_t)wid * HID + l * 8);
    float b8[8] = {bf2f(bb.x & 0xffff), bf2f(bb.x >> 16),
                   bf2f(bb.y & 0xffff), bf2f(bb.y >> 16),
                   bf2f(bb.z & 0xffff), bf2f(bb.z >> 16),
                   bf2f(bb.w & 0xffff), bf2f(bb.w >> 16)};
    float w2f[16];
    #pragma unroll
    for (int t = 0; t < 4; ++t)
        *reinterpret_cast<float4*>(&w2f[t * 4]) =
            *reinterpret_cast<const float4*>(w2 + l * 16 + t * 4);
    const float bias0 = b2[0], bias1 = b2[1];
    for (int e = start + q; e < end; e += 4) {
        int s = eidx[e];
        const uint4 aa = *reinterpret_cast<const uint4*>(Ah + (size_t)s * HID + l * 8);
        float a8[8] = {bf2f(aa.x & 0xffff), bf2f(aa.x >> 16),
                       bf2f(aa.y & 0xffff), bf2f(aa.y >> 16),
                       bf2f(aa.z & 0xffff), bf2f(aa.z >> 16),
                       bf2f(aa.w & 0xffff), bf2f(aa.w >> 16)};
        float s0 = 0.f, s1 = 0.f;
        #pragma unroll
        for (int j = 0; j < 8; ++j) {
            float z = fmaxf(a8[j] + b8[j], 0.f);
            s0 = fmaf(z, w2f[j * 2], s0);
            s1 = fmaf(z, w2f[j * 2 + 1], s1);
        }
        #pragma unroll
        for (int m = 8; m >= 1; m >>= 1) {
            s0 += __shfl_xor(s0, m);
            s1 += __shfl_xor(s1, m);
        }
        if (l == 0) {
            int oe = epos[e];
            float o0 = s0 + bias0, o1 = s1 + bias1;
            if (accumulate) {
                out[oe * 2 + 0] += o0;
                out[oe * 2 + 1] += o1;
            } else {
                out[oe * 2 + 0] = o0;
                out[oe * 2 + 1] = o1;
            }
        }
    }
}

// ---------------------------------------------------------------- launch
extern "C" void kernel_launch(void* const* d_in, const int* in_sizes, int n_in,
                              void* d_out, int out_size, void* d_ws, size_t ws_size,
                              hipStream_t stream)
{
    const float* h        = (const float*)d_in[0];
    const int*   src      = (const int*)d_in[1];
    const int*   dst      = (const int*)d_in[2];
    const float* emb_w    = (const float*)d_in[3];
    const float* emb_b    = (const float*)d_in[4];
    const float* eps      = (const float*)d_in[5];
    const float* mlp_w1   = (const float*)d_in[6];
    const float* mlp_b1   = (const float*)d_in[7];
    const float* mlp_bn_g = (const float*)d_in[8];
    const float* mlp_bn_b = (const float*)d_in[9];
    const float* mlp_w2   = (const float*)d_in[10];
    const float* mlp_b2   = (const float*)d_in[11];
    const float* app_bn_g = (const float*)d_in[12];
    const float* app_bn_b = (const float*)d_in[13];
    const float* gin_bn_g = (const float*)d_in[14];
    const float* gin_bn_b = (const float*)d_in[15];
    const float* pred_w1  = (const float*)d_in[16];
    const float* pred_b1  = (const float*)d_in[17];
    const float* pred_w2  = (const float*)d_in[18];
    const float* pred_b2  = (const float*)d_in[19];
    float* out = (float*)d_out;

    float* ws   = (float*)d_ws;
    float* x    = ws;                       // [N,128] f32
    float* tmp1 = ws + NH;                  // [N,128] f32
    float* tmp2 = ws + 2 * (size_t)NH;      // [N,128] f32, aliased by bf16 A,B
    float* sums = ws + 3 * (size_t)NH;      // [12][256]
    int*   off  = (int*)(sums + 12 * 256);  // [N]
    int*   deg  = off + NNODES;             // [N]
    int*   epos = deg + NNODES;             // [E]
    u16*   eidx = (u16*)(epos + NEDGES);    // [E]
    u16*   ah   = (u16*)tmp2;               // [N,128] bf16 (aliases tmp2 low half)
    u16*   bh   = ah + NH;                  // [N,128] bf16 (aliases tmp2 high half)
    size_t used_bytes = ((size_t)3 * NH + 12 * 256) * 4 + 2ull * NNODES * 4
                        + (size_t)NEDGES * 4 + (size_t)NEDGES * 2;
    u16* xh = (used_bytes + (size_t)NH * 2 <= ws_size) ? (eidx + NEDGES) : nullptr;

    const int NB = NH / 256;                    // 10000
    const int EB = NEDGES / 256;                // 1250
    const int GB = NNODES / ROWS;               // 500
    const int AGB = NNODES * 16 / 256;          // 1250
    const int ASB = NNODES / 16;                // 1250 (k_app_stat: 16 rows/block)
    const int CEB = NNODES / 4;                 // 5000

    // ---- CSR build (graph static across layers)
    hipMemsetAsync(deg, 0, NNODES * sizeof(int), stream);
    hipMemsetAsync(sums, 0, 12 * 256 * sizeof(float), stream);
    k_hist<<<EB, 256, 0, stream>>>(dst, deg);
    k_scan<<<1, 1024, 0, stream>>>(deg, off);
    k_fill<<<EB, 256, 0, stream>>>(src, dst, off, eidx, epos);

    k_embed<<<NB, 256, 0, stream>>>(h, emb_w, emb_b, x, xh);

    // head 0
    k_gemm_head<<<GB, 256, 0, stream>>>(x, pred_w1, pred_b1, ah, bh);
    k_edge_csr<<<CEB, 256, 0, stream>>>(ah, bh, off, eidx, epos,
                                        pred_w2, pred_b2, out, 0);

    for (int i = 0; i < NL; ++i) {
        float* s0 = sums + (i * 3 + 0) * 256;
        float* s1 = sums + (i * 3 + 1) * 256;
        float* s2 = sums + (i * 3 + 2) * 256;

        // t = (1+eps)*x + sum_in x[src]  (bf16 neighbor reads)
        k_gather<<<AGB, 256, 0, stream>>>(x, xh, off, eidx, eps, i, tmp1);

        // u = t @ W1 + b1 ; stats(u) -> s0
        k_gemm_stat<<<GB, 256, 0, stream>>>(tmp1, mlp_w1 + (size_t)i * HID * HID,
                                            mlp_b1 + i * HID, tmp2, s0);
        // v = relu(BN_s0(u)) @ W2 + b2 ; stats(v) -> s1
        k_gemm_bnin_stat<<<GB, 256, 0, stream>>>(tmp2, s0, mlp_bn_g + i * HID,
                                                 mlp_bn_b + i * HID,
                                                 mlp_w2 + (size_t)i * HID * HID,
                                                 mlp_b2 + i * HID, tmp1, s1);
        // stats(relu(BN_s1(v))) -> s2
        k_app_stat<<<ASB, 256, 0, stream>>>(tmp1, s1, app_bn_g + i * HID,
                                            app_bn_b + i * HID, s2);
        // x += relu(BN_s2(relu(BN_s1(v)))) fused into head GEMM staging;
        // A,B (bf16) overwrite tmp2 (u is dead). Per-block row ownership.
        k_head_resid<<<GB, 256, 0, stream>>>(tmp1, s1, app_bn_g + i * HID,
                                             app_bn_b + i * HID, s2,
                                             gin_bn_g + i * HID, gin_bn_b + i * HID,
                                             x, xh,
                                             pred_w1 + (size_t)(i + 1) * 256 * HID,
                                             pred_b1 + (i + 1) * HID, ah, bh);
        k_edge_csr<<<CEB, 256, 0, stream>>>(ah, bh, off, eidx, epos,
                                            pred_w2 + (i + 1) * HID * 2,
                                            pred_b2 + (i + 1) * 2, out, 1);
    }
}